// Round 1
// baseline (1556.906 us; speedup 1.0000x reference)
//
#include <hip/hip_runtime.h>
#include <math.h>

#define BB 2
#define SS 2048
#define DD 1024
#define NH 16
#define HDM 64
#define RNK 8

// ---------------------------------------------------------------------------
// z-pool: zsum[b][d] += sum over 64 rows of x  (mean applied later)
// ---------------------------------------------------------------------------
__global__ __launch_bounds__(256) void z_pool(const float* __restrict__ x,
                                              float* __restrict__ zsum) {
  int b = blockIdx.x;
  int s0 = blockIdx.y * 64;
  int tid = threadIdx.x;
  float p0 = 0.f, p1 = 0.f, p2 = 0.f, p3 = 0.f;
  const float* xp = x + ((size_t)b * SS + s0) * DD;
  for (int s = 0; s < 64; ++s) {
    const float* row = xp + (size_t)s * DD;
    p0 += row[tid];
    p1 += row[tid + 256];
    p2 += row[tid + 512];
    p3 += row[tid + 768];
  }
  atomicAdd(&zsum[b * DD + tid], p0);
  atomicAdd(&zsum[b * DD + tid + 256], p1);
  atomicAdd(&zsum[b * DD + tid + 512], p2);
  atomicAdd(&zsum[b * DD + tid + 768], p3);
}

// ---------------------------------------------------------------------------
// hyper_gen: per (path, batch) block -> z -> h=silu(z@w1+b1) -> c=h@w2+b2
//            -> A (8,1024) and Bm (1024,8)
// ---------------------------------------------------------------------------
__global__ __launch_bounds__(256) void hyper_gen(
    const float* __restrict__ zsum,
    const float* __restrict__ kw1, const float* __restrict__ kb1,
    const float* __restrict__ kw2, const float* __restrict__ kb2,
    const float* __restrict__ kgAw, const float* __restrict__ kgAb,
    const float* __restrict__ kgBw, const float* __restrict__ kgBb,
    const float* __restrict__ vw1, const float* __restrict__ vb1,
    const float* __restrict__ vw2, const float* __restrict__ vb2,
    const float* __restrict__ vgAw, const float* __restrict__ vgAb,
    const float* __restrict__ vgBw, const float* __restrict__ vgBb,
    float* __restrict__ Ak, float* __restrict__ Bk,
    float* __restrict__ Av, float* __restrict__ Bv) {
  int p = blockIdx.x >> 1;
  int b = blockIdx.x & 1;
  const float* w1  = p ? vw1  : kw1;
  const float* b1  = p ? vb1  : kb1;
  const float* w2  = p ? vw2  : kw2;
  const float* b2  = p ? vb2  : kb2;
  const float* gAw = p ? vgAw : kgAw;
  const float* gAb = p ? vgAb : kgAb;
  const float* gBw = p ? vgBw : kgBw;
  const float* gBb = p ? vgBb : kgBb;
  float* Aout = (p ? Av : Ak) + b * (RNK * DD);
  float* Bout = (p ? Bv : Bk) + b * (DD * RNK);

  __shared__ float zs[DD];
  __shared__ float hs[256];
  __shared__ float cs[64];
  int tid = threadIdx.x;
  for (int d = tid; d < DD; d += 256)
    zs[d] = zsum[b * DD + d] * (1.0f / (float)SS);
  __syncthreads();

  float acc = b1[tid];
  for (int j = 0; j < DD; ++j) acc += zs[j] * w1[j * 256 + tid];
  hs[tid] = acc / (1.0f + expf(-acc));  // silu
  __syncthreads();

  if (tid < 64) {
    float a = b2[tid];
    for (int j = 0; j < 256; ++j) a += hs[j] * w2[j * 64 + tid];
    cs[tid] = a;
  }
  __syncthreads();

  for (int idx = tid; idx < RNK * DD; idx += 256) {
    float a  = gAb[idx];
    float bb = gBb[idx];
    for (int j = 0; j < 64; ++j) {
      a  += cs[j] * gAw[j * (RNK * DD) + idx];
      bb += cs[j] * gBw[j * (DD * RNK) + idx];
    }
    Aout[idx] = a;
    Bout[idx] = bb;
  }
}

// ---------------------------------------------------------------------------
// xa[b,s,r] = dot(x[b,s,:], A[b,r,:]) for both k and v paths
// one block per (b,s), 16 groups of 16 lanes
// ---------------------------------------------------------------------------
__global__ __launch_bounds__(256) void xa_kernel(
    const float* __restrict__ x,
    const float* __restrict__ Ak, const float* __restrict__ Av,
    float* __restrict__ xak, float* __restrict__ xav) {
  int bs = blockIdx.x;          // 0..B*S-1
  int b = bs >> 11;
  __shared__ float xrow[DD];
  int tid = threadIdx.x;
  ((float4*)xrow)[tid] = ((const float4*)(x + (size_t)bs * DD))[tid];
  __syncthreads();
  int g = tid >> 4;     // 0..15
  int l16 = tid & 15;
  int p = g >> 3;       // 0 = k, 1 = v
  int r = g & 7;
  const float* Ar = (p ? Av : Ak) + ((size_t)(b * RNK + r) << 10);
  float acc = 0.f;
  for (int d = l16; d < DD; d += 16) acc += xrow[d] * Ar[d];
#pragma unroll
  for (int off = 8; off; off >>= 1) acc += __shfl_xor(acc, off, 16);
  if (l16 == 0) (p ? xav : xak)[bs * RNK + r] = acc;
}

// ---------------------------------------------------------------------------
// dyn-add (optional) + RoPE (optional), in-place on t (B,S,D)
// one thread per rotation pair
// ---------------------------------------------------------------------------
__global__ __launch_bounds__(256) void dyn_rope(
    float* __restrict__ t, const float* __restrict__ xa,
    const float* __restrict__ Bm, int do_rope) {
  int gid = blockIdx.x * 256 + threadIdx.x;  // < 2*2048*512
  int i = gid & 31;
  int h = (gid >> 5) & 15;
  int s = (gid >> 9) & 2047;
  int b = gid >> 20;
  int o1 = h * HDM + i;
  int o2 = o1 + 32;
  size_t base = ((size_t)(b * SS + s)) << 10;
  float v1 = t[base + o1];
  float v2 = t[base + o2];
  if (xa) {
    const float* xr = &xa[(size_t)(b * SS + s) * RNK];
    float4 x0 = *(const float4*)xr;
    float4 x1 = *(const float4*)(xr + 4);
    const float* bp1 = &Bm[(size_t)(b * DD + o1) * RNK];
    float4 A0 = *(const float4*)bp1;
    float4 A1 = *(const float4*)(bp1 + 4);
    const float* bp2 = &Bm[(size_t)(b * DD + o2) * RNK];
    float4 B0 = *(const float4*)bp2;
    float4 B1 = *(const float4*)(bp2 + 4);
    float d1 = x0.x * A0.x + x0.y * A0.y + x0.z * A0.z + x0.w * A0.w +
               x1.x * A1.x + x1.y * A1.y + x1.z * A1.z + x1.w * A1.w;
    float d2 = x0.x * B0.x + x0.y * B0.y + x0.z * B0.z + x0.w * B0.w +
               x1.x * B1.x + x1.y * B1.y + x1.z * B1.z + x1.w * B1.w;
    v1 += d1 * (1.0f / RNK);
    v2 += d2 * (1.0f / RNK);
  }
  if (do_rope) {
    // inv freq = 10000^(-i/32) = exp(-i * ln(10000)/32)
    float freq = expf(-(float)i * (9.210340371976184f / 32.0f));
    float ang = (float)s * freq;
    float sn, cn;
    sincosf(ang, &sn, &cn);
    float n1 = v1 * cn - v2 * sn;
    float n2 = v2 * cn + v1 * sn;
    v1 = n1;
    v2 = n2;
  }
  t[base + o1] = v1;
  t[base + o2] = v2;
}

// ---------------------------------------------------------------------------
// fp32 tiled GEMM: C[M,N] = A[M,K] @ W[K,N] + bias, 64x64 tile, 4x4/thread
// ---------------------------------------------------------------------------
__global__ __launch_bounds__(256) void gemm_bias(
    const float* __restrict__ A, const float* __restrict__ W,
    const float* __restrict__ bias, float* __restrict__ C,
    int M, int K, int N) {
  __shared__ float As[16][68];
  __shared__ float Bs[16][68];
  int tid = threadIdx.x;
  int bm = blockIdx.x * 64;
  int bn = blockIdx.y * 64;
  int tx = tid & 15, ty = tid >> 4;
  float acc[4][4] = {};
  int am = tid >> 2, ak = (tid & 3) * 4;
  int bkk = tid >> 4, bn4 = (tid & 15) * 4;
  const float* Aptr = A + (size_t)(bm + am) * K + ak;
  const float* Wptr = W + (size_t)bkk * N + bn + bn4;
  for (int k0 = 0; k0 < K; k0 += 16) {
    float4 a4 = *(const float4*)(Aptr + k0);
    float4 b4 = *(const float4*)(Wptr + (size_t)k0 * N);
    As[ak + 0][am] = a4.x;
    As[ak + 1][am] = a4.y;
    As[ak + 2][am] = a4.z;
    As[ak + 3][am] = a4.w;
    *(float4*)&Bs[bkk][bn4] = b4;
    __syncthreads();
#pragma unroll
    for (int kk = 0; kk < 16; ++kk) {
      float4 av4 = *(const float4*)&As[kk][ty * 4];
      float4 bv4 = *(const float4*)&Bs[kk][tx * 4];
      float avv[4] = {av4.x, av4.y, av4.z, av4.w};
      float bvv[4] = {bv4.x, bv4.y, bv4.z, bv4.w};
#pragma unroll
      for (int mi = 0; mi < 4; ++mi)
#pragma unroll
        for (int ni = 0; ni < 4; ++ni) acc[mi][ni] += avv[mi] * bvv[ni];
    }
    __syncthreads();
  }
  float4 bias4 = *(const float4*)&bias[bn + tx * 4];
  float bvv[4] = {bias4.x, bias4.y, bias4.z, bias4.w};
#pragma unroll
  for (int mi = 0; mi < 4; ++mi) {
    float4 o;
    o.x = acc[mi][0] + bvv[0];
    o.y = acc[mi][1] + bvv[1];
    o.z = acc[mi][2] + bvv[2];
    o.w = acc[mi][3] + bvv[3];
    *(float4*)&C[(size_t)(bm + ty * 4 + mi) * N + bn + tx * 4] = o;
  }
}

// ---------------------------------------------------------------------------
// causal flash attention, fp32. One block = (b,h, 32-query tile).
// 64-key tiles, online softmax. Output overwrites q in-place.
// ---------------------------------------------------------------------------
__global__ __launch_bounds__(256) void attn_causal(
    float* __restrict__ q, const float* __restrict__ k,
    const float* __restrict__ v) {
  __shared__ float Qs[32][68];
  __shared__ float Ks[64][68];
  __shared__ float Vs[64][68];
  __shared__ float Ps[32][68];
  int bh = blockIdx.x;
  int b = bh >> 4, h = bh & 15;
  int q0 = blockIdx.y * 32;
  int tid = threadIdx.x;
  const float* kbase = k + ((size_t)b * SS) * DD + h * HDM;
  const float* vbase = v + ((size_t)b * SS) * DD + h * HDM;
  float* qbase = q + ((size_t)b * SS) * DD + h * HDM;

  // load Q tile (32 x 64)
#pragma unroll
  for (int l = 0; l < 2; ++l) {
    int idx = tid + 256 * l;
    int r = idx >> 4, d4 = (idx & 15) * 4;
    *(float4*)&Qs[r][d4] = *(const float4*)&qbase[(size_t)(q0 + r) * DD + d4];
  }

  int i = tid >> 3;  // query row 0..31
  int g = tid & 7;   // 8 lanes per row
  float oa[8];
#pragma unroll
  for (int u = 0; u < 8; ++u) oa[u] = 0.f;
  float m_run = -1e30f, l_run = 0.f;
  int nkt = (q0 >> 6) + 1;

  for (int kt = 0; kt < nkt; ++kt) {
    __syncthreads();
#pragma unroll
    for (int l = 0; l < 4; ++l) {
      int idx = tid + 256 * l;
      int r = idx >> 4, d4 = (idx & 15) * 4;
      *(float4*)&Ks[r][d4] =
          *(const float4*)&kbase[(size_t)(kt * 64 + r) * DD + d4];
      *(float4*)&Vs[r][d4] =
          *(const float4*)&vbase[(size_t)(kt * 64 + r) * DD + d4];
    }
    __syncthreads();

    float sv[8];
#pragma unroll
    for (int jj = 0; jj < 8; ++jj) sv[jj] = 0.f;
    for (int d4 = 0; d4 < 64; d4 += 4) {
      float4 q4 = *(const float4*)&Qs[i][d4];
#pragma unroll
      for (int jj = 0; jj < 8; ++jj) {
        float4 k4 = *(const float4*)&Ks[jj * 8 + g][d4];
        sv[jj] += q4.x * k4.x + q4.y * k4.y + q4.z * k4.z + q4.w * k4.w;
      }
    }
    int iglob = q0 + i;
    float mloc = -1e30f;
#pragma unroll
    for (int jj = 0; jj < 8; ++jj) {
      int jglob = kt * 64 + jj * 8 + g;
      float s = sv[jj] * 0.125f;  // 1/sqrt(64)
      if (jglob > iglob) s = -1e30f;
      sv[jj] = s;
      mloc = fmaxf(mloc, s);
    }
#pragma unroll
    for (int off = 4; off; off >>= 1)
      mloc = fmaxf(mloc, __shfl_xor(mloc, off, 8));
    float m_new = fmaxf(m_run, mloc);
    float alpha = expf(m_run - m_new);
    float psum = 0.f;
#pragma unroll
    for (int jj = 0; jj < 8; ++jj) {
      float pv = expf(sv[jj] - m_new);
      Ps[i][jj * 8 + g] = pv;
      psum += pv;
    }
#pragma unroll
    for (int off = 4; off; off >>= 1) psum += __shfl_xor(psum, off, 8);
    l_run = l_run * alpha + psum;
    m_run = m_new;
#pragma unroll
    for (int u = 0; u < 8; ++u) oa[u] *= alpha;
    // Ps row i written & read only by this wave's 8 lanes -> no barrier
    for (int j = 0; j < 64; ++j) {
      float pj = Ps[i][j];
      float4 va = *(const float4*)&Vs[j][g * 8];
      float4 vb4 = *(const float4*)&Vs[j][g * 8 + 4];
      oa[0] += pj * va.x;
      oa[1] += pj * va.y;
      oa[2] += pj * va.z;
      oa[3] += pj * va.w;
      oa[4] += pj * vb4.x;
      oa[5] += pj * vb4.y;
      oa[6] += pj * vb4.z;
      oa[7] += pj * vb4.w;
    }
  }
  float invl = 1.0f / l_run;
  float4 o0 = make_float4(oa[0] * invl, oa[1] * invl, oa[2] * invl, oa[3] * invl);
  float4 o1 = make_float4(oa[4] * invl, oa[5] * invl, oa[6] * invl, oa[7] * invl);
  *(float4*)&qbase[(size_t)(q0 + i) * DD + g * 8] = o0;
  *(float4*)&qbase[(size_t)(q0 + i) * DD + g * 8 + 4] = o1;
}

// ---------------------------------------------------------------------------
extern "C" void kernel_launch(void* const* d_in, const int* in_sizes, int n_in,
                              void* d_out, int out_size, void* d_ws,
                              size_t ws_size, hipStream_t stream) {
  const float* x    = (const float*)d_in[0];
  const float* Wq   = (const float*)d_in[1];
  const float* bq   = (const float*)d_in[2];
  const float* Wo   = (const float*)d_in[3];
  const float* bo   = (const float*)d_in[4];
  const float* Wk   = (const float*)d_in[5];
  const float* bk   = (const float*)d_in[6];
  const float* kw1  = (const float*)d_in[7];
  const float* kb1  = (const float*)d_in[8];
  const float* kw2  = (const float*)d_in[9];
  const float* kb2  = (const float*)d_in[10];
  const float* kgAw = (const float*)d_in[11];
  const float* kgAb = (const float*)d_in[12];
  const float* kgBw = (const float*)d_in[13];
  const float* kgBb = (const float*)d_in[14];
  const float* Wv   = (const float*)d_in[15];
  const float* bv   = (const float*)d_in[16];
  const float* vw1  = (const float*)d_in[17];
  const float* vb1  = (const float*)d_in[18];
  const float* vw2  = (const float*)d_in[19];
  const float* vb2  = (const float*)d_in[20];
  const float* vgAw = (const float*)d_in[21];
  const float* vgAb = (const float*)d_in[22];
  const float* vgBw = (const float*)d_in[23];
  const float* vgBb = (const float*)d_in[24];
  float* out = (float*)d_out;

  float* ws = (float*)d_ws;
  const size_t NTOK = (size_t)BB * SS * DD;  // 4M
  float* qb  = ws;
  float* kb_ = qb + NTOK;
  float* vb_ = kb_ + NTOK;
  float* Ak  = vb_ + NTOK;
  float* Bk  = Ak + BB * RNK * DD;
  float* Av  = Bk + BB * DD * RNK;
  float* Bv  = Av + BB * RNK * DD;
  float* xak = Bv + BB * DD * RNK;
  float* xav = xak + BB * SS * RNK;
  float* zsum = xav + BB * SS * RNK;

  hipMemsetAsync(zsum, 0, BB * DD * sizeof(float), stream);
  z_pool<<<dim3(BB, SS / 64), 256, 0, stream>>>(x, zsum);
  hyper_gen<<<4, 256, 0, stream>>>(zsum, kw1, kb1, kw2, kb2, kgAw, kgAb, kgBw,
                                   kgBb, vw1, vb1, vw2, vb2, vgAw, vgAb, vgBw,
                                   vgBb, Ak, Bk, Av, Bv);
  // static projections
  gemm_bias<<<dim3(64, 16), 256, 0, stream>>>(x, Wq, bq, qb, BB * SS, DD, DD);
  gemm_bias<<<dim3(64, 16), 256, 0, stream>>>(x, Wk, bk, kb_, BB * SS, DD, DD);
  gemm_bias<<<dim3(64, 16), 256, 0, stream>>>(x, Wv, bv, vb_, BB * SS, DD, DD);
  // low-rank projections
  xa_kernel<<<BB * SS, 256, 0, stream>>>(x, Ak, Av, xak, xav);
  // dyn add + rope
  int nrp = (BB * SS * DD / 2) / 256;
  dyn_rope<<<nrp, 256, 0, stream>>>(qb, nullptr, nullptr, 1);
  dyn_rope<<<nrp, 256, 0, stream>>>(kb_, xak, Bk, 1);
  dyn_rope<<<nrp, 256, 0, stream>>>(vb_, xav, Bv, 0);
  // attention (writes o into qb in-place)
  attn_causal<<<dim3(BB * NH, SS / 32), 256, 0, stream>>>(qb, kb_, vb_);
  // output projection
  gemm_bias<<<dim3(64, 16), 256, 0, stream>>>(qb, Wo, bo, out, BB * SS, DD, DD);
}

// Round 2
// 736.392 us; speedup vs baseline: 2.1142x; 2.1142x over previous
//
#include <hip/hip_runtime.h>
#include <math.h>

#define BB 2
#define SS 2048
#define DD 1024
#define NH 16
#define HDM 64
#define RNK 8

typedef short short8 __attribute__((ext_vector_type(8)));
typedef float floatx4 __attribute__((ext_vector_type(4)));

static __device__ __forceinline__ ushort f2bf(float f) {
  union { float f; unsigned u; } v;
  v.f = f;
  unsigned r = (v.u + 0x7FFFu + ((v.u >> 16) & 1u)) >> 16;
  return (ushort)r;
}

// ---------------------------------------------------------------------------
// z-pool: zsum[b][d] += sum over 64 rows of x
// ---------------------------------------------------------------------------
__global__ __launch_bounds__(256) void z_pool(const float* __restrict__ x,
                                              float* __restrict__ zsum) {
  int b = blockIdx.x;
  int s0 = blockIdx.y * 64;
  int tid = threadIdx.x;
  float p0 = 0.f, p1 = 0.f, p2 = 0.f, p3 = 0.f;
  const float* xp = x + ((size_t)b * SS + s0) * DD;
  for (int s = 0; s < 64; ++s) {
    const float* row = xp + (size_t)s * DD;
    p0 += row[tid];
    p1 += row[tid + 256];
    p2 += row[tid + 512];
    p3 += row[tid + 768];
  }
  atomicAdd(&zsum[b * DD + tid], p0);
  atomicAdd(&zsum[b * DD + tid + 256], p1);
  atomicAdd(&zsum[b * DD + tid + 512], p2);
  atomicAdd(&zsum[b * DD + tid + 768], p3);
}

// ---------------------------------------------------------------------------
// hyper_gen: z -> h=silu(z@w1+b1) -> c=h@w2+b2 -> A (8,1024), Bm (1024,8)
// ---------------------------------------------------------------------------
__global__ __launch_bounds__(256) void hyper_gen(
    const float* __restrict__ zsum,
    const float* __restrict__ kw1, const float* __restrict__ kb1,
    const float* __restrict__ kw2, const float* __restrict__ kb2,
    const float* __restrict__ kgAw, const float* __restrict__ kgAb,
    const float* __restrict__ kgBw, const float* __restrict__ kgBb,
    const float* __restrict__ vw1, const float* __restrict__ vb1,
    const float* __restrict__ vw2, const float* __restrict__ vb2,
    const float* __restrict__ vgAw, const float* __restrict__ vgAb,
    const float* __restrict__ vgBw, const float* __restrict__ vgBb,
    float* __restrict__ Ak, float* __restrict__ Bk,
    float* __restrict__ Av, float* __restrict__ Bv) {
  int p = blockIdx.x >> 1;
  int b = blockIdx.x & 1;
  const float* w1  = p ? vw1  : kw1;
  const float* b1  = p ? vb1  : kb1;
  const float* w2  = p ? vw2  : kw2;
  const float* b2  = p ? vb2  : kb2;
  const float* gAw = p ? vgAw : kgAw;
  const float* gAb = p ? vgAb : kgAb;
  const float* gBw = p ? vgBw : kgBw;
  const float* gBb = p ? vgBb : kgBb;
  float* Aout = (p ? Av : Ak) + b * (RNK * DD);
  float* Bout = (p ? Bv : Bk) + b * (DD * RNK);

  __shared__ float zs[DD];
  __shared__ float hs[256];
  __shared__ float cs[64];
  int tid = threadIdx.x;
  for (int d = tid; d < DD; d += 256)
    zs[d] = zsum[b * DD + d] * (1.0f / (float)SS);
  __syncthreads();

  float acc = b1[tid];
  for (int j = 0; j < DD; ++j) acc += zs[j] * w1[j * 256 + tid];
  hs[tid] = acc / (1.0f + expf(-acc));
  __syncthreads();

  if (tid < 64) {
    float a = b2[tid];
    for (int j = 0; j < 256; ++j) a += hs[j] * w2[j * 64 + tid];
    cs[tid] = a;
  }
  __syncthreads();

  for (int idx = tid; idx < RNK * DD; idx += 256) {
    float a  = gAb[idx];
    float bb = gBb[idx];
    for (int j = 0; j < 64; ++j) {
      a  += cs[j] * gAw[j * (RNK * DD) + idx];
      bb += cs[j] * gBw[j * (DD * RNK) + idx];
    }
    Aout[idx] = a;
    Bout[idx] = bb;
  }
}

// ---------------------------------------------------------------------------
// xa[b,s,r] = dot(x[b,s,:], A[b,r,:]) for both k and v paths
// ---------------------------------------------------------------------------
__global__ __launch_bounds__(256) void xa_kernel(
    const float* __restrict__ x,
    const float* __restrict__ Ak, const float* __restrict__ Av,
    float* __restrict__ xak, float* __restrict__ xav) {
  int bs = blockIdx.x;
  int b = bs >> 11;
  __shared__ float xrow[DD];
  int tid = threadIdx.x;
  ((float4*)xrow)[tid] = ((const float4*)(x + (size_t)bs * DD))[tid];
  __syncthreads();
  int g = tid >> 4;
  int l16 = tid & 15;
  int p = g >> 3;
  int r = g & 7;
  const float* Ar = (p ? Av : Ak) + ((size_t)(b * RNK + r) << 10);
  float acc = 0.f;
  for (int d = l16; d < DD; d += 16) acc += xrow[d] * Ar[d];
#pragma unroll
  for (int off = 8; off; off >>= 1) acc += __shfl_xor(acc, off, 16);
  if (l16 == 0) (p ? xav : xak)[bs * RNK + r] = acc;
}

// ---------------------------------------------------------------------------
// cvt_bf16: fp32 -> bf16, same layout, 4 elements / thread
// ---------------------------------------------------------------------------
__global__ __launch_bounds__(256) void cvt_bf16(const float* __restrict__ in,
                                                ushort* __restrict__ out) {
  int gid = blockIdx.x * 256 + threadIdx.x;
  float4 a = ((const float4*)in)[gid];
  ushort4 o;
  o.x = f2bf(a.x);
  o.y = f2bf(a.y);
  o.z = f2bf(a.z);
  o.w = f2bf(a.w);
  ((ushort4*)out)[gid] = o;
}

// ---------------------------------------------------------------------------
// cvt_wt: W fp32 [K=1024][N=1024] -> Wt bf16 [N][K] (transpose + convert)
// ---------------------------------------------------------------------------
__global__ __launch_bounds__(256) void cvt_wt(const float* __restrict__ W,
                                              ushort* __restrict__ Wt) {
  __shared__ float tile[32][33];
  int bx = blockIdx.x, by = blockIdx.y;
  int tx = threadIdx.x & 31, ty = threadIdx.x >> 5;
#pragma unroll
  for (int i = 0; i < 4; ++i)
    tile[ty + 8 * i][tx] = W[(size_t)(by * 32 + ty + 8 * i) * DD + bx * 32 + tx];
  __syncthreads();
#pragma unroll
  for (int i = 0; i < 4; ++i)
    Wt[(size_t)(bx * 32 + ty + 8 * i) * DD + by * 32 + tx] =
        f2bf(tile[tx][ty + 8 * i]);
}

// ---------------------------------------------------------------------------
// dyn-add (optional) + RoPE (optional) + pack to bf16 head-major [b][h][s][hd]
// ---------------------------------------------------------------------------
__global__ __launch_bounds__(256) void dyn_rope_pack(
    const float* __restrict__ t, const float* __restrict__ xa,
    const float* __restrict__ Bm, ushort* __restrict__ th, int do_rope) {
  int gid = blockIdx.x * 256 + threadIdx.x;
  int i = gid & 31;
  int h = (gid >> 5) & 15;
  int s = (gid >> 9) & 2047;
  int b = gid >> 20;
  int o1 = h * HDM + i;
  int o2 = o1 + 32;
  size_t base = ((size_t)(b * SS + s)) << 10;
  float v1 = t[base + o1];
  float v2 = t[base + o2];
  if (xa) {
    const float* xr = &xa[(size_t)(b * SS + s) * RNK];
    float4 x0 = *(const float4*)xr;
    float4 x1 = *(const float4*)(xr + 4);
    const float* bp1 = &Bm[(size_t)(b * DD + o1) * RNK];
    float4 A0 = *(const float4*)bp1;
    float4 A1 = *(const float4*)(bp1 + 4);
    const float* bp2 = &Bm[(size_t)(b * DD + o2) * RNK];
    float4 B0 = *(const float4*)bp2;
    float4 B1 = *(const float4*)(bp2 + 4);
    float d1 = x0.x * A0.x + x0.y * A0.y + x0.z * A0.z + x0.w * A0.w +
               x1.x * A1.x + x1.y * A1.y + x1.z * A1.z + x1.w * A1.w;
    float d2 = x0.x * B0.x + x0.y * B0.y + x0.z * B0.z + x0.w * B0.w +
               x1.x * B1.x + x1.y * B1.y + x1.z * B1.z + x1.w * B1.w;
    v1 += d1 * (1.0f / RNK);
    v2 += d2 * (1.0f / RNK);
  }
  if (do_rope) {
    float freq = expf(-(float)i * (9.210340371976184f / 32.0f));
    float ang = (float)s * freq;
    float sn, cn;
    sincosf(ang, &sn, &cn);
    float n1 = v1 * cn - v2 * sn;
    float n2 = v2 * cn + v1 * sn;
    v1 = n1;
    v2 = n2;
  }
  size_t ob = ((size_t)(b * NH + h) * SS + s) * HDM + i;
  th[ob] = f2bf(v1);
  th[ob + 32] = f2bf(v2);
}

// ---------------------------------------------------------------------------
// bf16 MFMA GEMM: C[M][N] = A[M][K] @ Bt[N][K]^T + bias  (C fp32)
// 128x128 tile, BK=32, 4 waves each 64x64
// ---------------------------------------------------------------------------
__global__ __launch_bounds__(256) void gemm_bf16(
    const ushort* __restrict__ A, const ushort* __restrict__ Bt,
    const float* __restrict__ bias, float* __restrict__ C,
    int M, int N, int K) {
  __shared__ ushort As[128][40];
  __shared__ ushort Bs[128][40];
  int tid = threadIdx.x;
  int bm = blockIdx.x * 128, bn = blockIdx.y * 128;
  int w = tid >> 6, lane = tid & 63, l16 = lane & 15, q4 = lane >> 4;
  int wm = (w >> 1) * 64, wn = (w & 1) * 64;
  floatx4 acc[4][4];
#pragma unroll
  for (int mi = 0; mi < 4; ++mi)
#pragma unroll
    for (int ni = 0; ni < 4; ++ni) acc[mi][ni] = 0;

  int sr = tid >> 2, sc = (tid & 3) * 8;
  const ushort* Ap0 = A + (size_t)(bm + sr) * K + sc;
  const ushort* Ap1 = A + (size_t)(bm + sr + 64) * K + sc;
  const ushort* Bp0 = Bt + (size_t)(bn + sr) * K + sc;
  const ushort* Bp1 = Bt + (size_t)(bn + sr + 64) * K + sc;

  for (int k0 = 0; k0 < K; k0 += 32) {
    uint4 a0 = *(const uint4*)(Ap0 + k0);
    uint4 a1 = *(const uint4*)(Ap1 + k0);
    uint4 b0 = *(const uint4*)(Bp0 + k0);
    uint4 b1 = *(const uint4*)(Bp1 + k0);
    __syncthreads();
    *(uint4*)&As[sr][sc] = a0;
    *(uint4*)&As[sr + 64][sc] = a1;
    *(uint4*)&Bs[sr][sc] = b0;
    *(uint4*)&Bs[sr + 64][sc] = b1;
    __syncthreads();
    short8 af[4], bf[4];
#pragma unroll
    for (int mi = 0; mi < 4; ++mi)
      af[mi] = *(const short8*)&As[wm + mi * 16 + l16][q4 * 8];
#pragma unroll
    for (int ni = 0; ni < 4; ++ni)
      bf[ni] = *(const short8*)&Bs[wn + ni * 16 + l16][q4 * 8];
#pragma unroll
    for (int mi = 0; mi < 4; ++mi)
#pragma unroll
      for (int ni = 0; ni < 4; ++ni)
        acc[mi][ni] = __builtin_amdgcn_mfma_f32_16x16x32_bf16(
            af[mi], bf[ni], acc[mi][ni], 0, 0, 0);
  }
#pragma unroll
  for (int mi = 0; mi < 4; ++mi) {
#pragma unroll
    for (int r = 0; r < 4; ++r) {
      int row = bm + wm + mi * 16 + q4 * 4 + r;
      float* Cr = C + (size_t)row * N;
#pragma unroll
      for (int ni = 0; ni < 4; ++ni) {
        int col = bn + wn + ni * 16 + l16;
        Cr[col] = acc[mi][ni][r] + bias[col];
      }
    }
  }
}

// ---------------------------------------------------------------------------
// MFMA flash attention (causal). Block = (b,h) x 64-query tile, 4 waves.
// q/k/v bf16 head-major [b][h][s][64]. Output bf16 [b][s][1024].
// ---------------------------------------------------------------------------
#define VT_IDX(d, c) ((unsigned)(72 * (d) + 16 * ((d) >> 3) + (c)))

__global__ __launch_bounds__(256) void attn_mfma(
    const ushort* __restrict__ qh, const ushort* __restrict__ kh,
    const ushort* __restrict__ vh, ushort* __restrict__ ao) {
  __shared__ ushort Ks[64][72];
  __shared__ ushort Vt[4720];
  __shared__ ushort Ps[64][72];
  int bh = blockIdx.x;
  int b = bh >> 4, h = bh & 15;
  int q0 = blockIdx.y * 64;
  int tid = threadIdx.x;
  int w = tid >> 6, lane = tid & 63, l16 = lane & 15, q4 = lane >> 4;

  const ushort* qrow =
      qh + ((size_t)bh * SS + q0 + 16 * w + l16) * HDM;
  short8 qf0 = *(const short8*)(qrow + q4 * 8);
  short8 qf1 = *(const short8*)(qrow + 32 + q4 * 8);

  floatx4 o[4];
#pragma unroll
  for (int ni = 0; ni < 4; ++ni) o[ni] = 0;
  float m_r[4], l_r[4];
#pragma unroll
  for (int r = 0; r < 4; ++r) {
    m_r[r] = -1e30f;
    l_r[r] = 0.f;
  }

  int nkt = (q0 >> 6) + 1;
  int skr = tid >> 2, skc = (tid & 3) * 8;
  int so8 = tid & 7, sp = tid >> 3;
  const ushort* kbase = kh + (size_t)bh * SS * HDM;
  const ushort* vbase = vh + (size_t)bh * SS * HDM;

  for (int kt = 0; kt < nkt; ++kt) {
    int k0 = kt * 64;
    __syncthreads();
    *(uint4*)&Ks[skr][skc] =
        *(const uint4*)(kbase + (size_t)(k0 + skr) * HDM + skc);
    *(uint4*)&Ks[skr][skc + 32] =
        *(const uint4*)(kbase + (size_t)(k0 + skr) * HDM + skc + 32);
    const ushort* v0 = vbase + (size_t)(k0 + 2 * sp) * HDM + so8 * 8;
    uint4 va = *(const uint4*)v0;
    uint4 vb = *(const uint4*)(v0 + HDM);
    const ushort* pa = (const ushort*)&va;
    const ushort* pb = (const ushort*)&vb;
#pragma unroll
    for (int j = 0; j < 8; ++j) {
      int d = so8 * 8 + j;
      *(unsigned*)&Vt[VT_IDX(d, 2 * sp)] =
          (unsigned)pa[j] | ((unsigned)pb[j] << 16);
    }
    __syncthreads();

    // QK^T -> s4[ni] (16 q-rows x 64 keys per wave)
    floatx4 s4[4];
#pragma unroll
    for (int ni = 0; ni < 4; ++ni) {
      short8 kf0 = *(const short8*)&Ks[ni * 16 + l16][q4 * 8];
      short8 kf1 = *(const short8*)&Ks[ni * 16 + l16][32 + q4 * 8];
      floatx4 c;
      c = 0;
      c = __builtin_amdgcn_mfma_f32_16x16x32_bf16(qf0, kf0, c, 0, 0, 0);
      c = __builtin_amdgcn_mfma_f32_16x16x32_bf16(qf1, kf1, c, 0, 0, 0);
      s4[ni] = c;
    }

    bool diag = (kt == nkt - 1);
    float sv[4][4];
#pragma unroll
    for (int ni = 0; ni < 4; ++ni) {
#pragma unroll
      for (int r = 0; r < 4; ++r) {
        float vvv = s4[ni][r] * 0.125f;
        if (diag) {
          int key = k0 + ni * 16 + l16;
          int qr = q0 + 16 * w + q4 * 4 + r;
          if (key > qr) vvv = -1e30f;
        }
        sv[ni][r] = vvv;
      }
    }
    float alpha[4];
#pragma unroll
    for (int r = 0; r < 4; ++r) {
      float mloc = fmaxf(fmaxf(sv[0][r], sv[1][r]), fmaxf(sv[2][r], sv[3][r]));
      mloc = fmaxf(mloc, __shfl_xor(mloc, 1));
      mloc = fmaxf(mloc, __shfl_xor(mloc, 2));
      mloc = fmaxf(mloc, __shfl_xor(mloc, 4));
      mloc = fmaxf(mloc, __shfl_xor(mloc, 8));
      float mn = fmaxf(m_r[r], mloc);
      alpha[r] = __expf(m_r[r] - mn);
      m_r[r] = mn;
      float ps = 0.f;
      int prow = 16 * w + q4 * 4 + r;
#pragma unroll
      for (int ni = 0; ni < 4; ++ni) {
        float p = __expf(sv[ni][r] - mn);
        Ps[prow][ni * 16 + l16] = f2bf(p);
        ps += p;
      }
      ps += __shfl_xor(ps, 1);
      ps += __shfl_xor(ps, 2);
      ps += __shfl_xor(ps, 4);
      ps += __shfl_xor(ps, 8);
      l_r[r] = l_r[r] * alpha[r] + ps;
#pragma unroll
      for (int ni = 0; ni < 4; ++ni) o[ni][r] *= alpha[r];
    }

    // PV
    short8 pf0 = *(const short8*)&Ps[16 * w + l16][q4 * 8];
    short8 pf1 = *(const short8*)&Ps[16 * w + l16][32 + q4 * 8];
#pragma unroll
    for (int ni = 0; ni < 4; ++ni) {
      short8 vf0 = *(const short8*)&Vt[VT_IDX(ni * 16 + l16, q4 * 8)];
      short8 vf1 = *(const short8*)&Vt[VT_IDX(ni * 16 + l16, 32 + q4 * 8)];
      o[ni] = __builtin_amdgcn_mfma_f32_16x16x32_bf16(pf0, vf0, o[ni], 0, 0, 0);
      o[ni] = __builtin_amdgcn_mfma_f32_16x16x32_bf16(pf1, vf1, o[ni], 0, 0, 0);
    }
  }

#pragma unroll
  for (int r = 0; r < 4; ++r) {
    float inv = 1.0f / l_r[r];
    int srow = q0 + 16 * w + q4 * 4 + r;
    ushort* orow = ao + ((size_t)b * SS + srow) * DD + h * HDM;
#pragma unroll
    for (int ni = 0; ni < 4; ++ni) orow[ni * 16 + l16] = f2bf(o[ni][r] * inv);
  }
}

// ---------------------------------------------------------------------------
extern "C" void kernel_launch(void* const* d_in, const int* in_sizes, int n_in,
                              void* d_out, int out_size, void* d_ws,
                              size_t ws_size, hipStream_t stream) {
  const float* x    = (const float*)d_in[0];
  const float* Wq   = (const float*)d_in[1];
  const float* bq   = (const float*)d_in[2];
  const float* Wo   = (const float*)d_in[3];
  const float* bo   = (const float*)d_in[4];
  const float* Wk   = (const float*)d_in[5];
  const float* bk   = (const float*)d_in[6];
  const float* kw1  = (const float*)d_in[7];
  const float* kb1  = (const float*)d_in[8];
  const float* kw2  = (const float*)d_in[9];
  const float* kb2  = (const float*)d_in[10];
  const float* kgAw = (const float*)d_in[11];
  const float* kgAb = (const float*)d_in[12];
  const float* kgBw = (const float*)d_in[13];
  const float* kgBb = (const float*)d_in[14];
  const float* Wv   = (const float*)d_in[15];
  const float* bv   = (const float*)d_in[16];
  const float* vw1  = (const float*)d_in[17];
  const float* vb1  = (const float*)d_in[18];
  const float* vw2  = (const float*)d_in[19];
  const float* vb2  = (const float*)d_in[20];
  const float* vgAw = (const float*)d_in[21];
  const float* vgAb = (const float*)d_in[22];
  const float* vgBw = (const float*)d_in[23];
  const float* vgBb = (const float*)d_in[24];
  float* out = (float*)d_out;

  char* ws = (char*)d_ws;
  const size_t MB = 1024 * 1024;
  float*  qf  = (float*)(ws);            // 16 MB fp32 scratch (q,k,v serially)
  ushort* aob = (ushort*)(ws);           // attn out bf16, aliases qf (dead)
  ushort* qhb = (ushort*)(ws + 16 * MB); // 8 MB
  ushort* khb = (ushort*)(ws + 24 * MB); // 8 MB
  ushort* vhb = (ushort*)(ws + 32 * MB); // 8 MB
  ushort* xb  = (ushort*)(ws + 40 * MB); // 8 MB
  ushort* Wtq = (ushort*)(ws + 48 * MB); // 2 MB each
  ushort* Wtk = (ushort*)(ws + 50 * MB);
  ushort* Wtv = (ushort*)(ws + 52 * MB);
  ushort* Wto = (ushort*)(ws + 54 * MB);
  float*  Ak  = (float*)(ws + 56 * MB);
  float*  Bk  = Ak + BB * RNK * DD;
  float*  Av  = Bk + BB * DD * RNK;
  float*  Bv  = Av + BB * RNK * DD;
  float*  xak = Bv + BB * DD * RNK;
  float*  xav = xak + BB * SS * RNK;
  float*  zsum = xav + BB * SS * RNK;

  hipMemsetAsync(zsum, 0, BB * DD * sizeof(float), stream);
  z_pool<<<dim3(BB, SS / 64), 256, 0, stream>>>(x, zsum);
  hyper_gen<<<4, 256, 0, stream>>>(zsum, kw1, kb1, kw2, kb2, kgAw, kgAb, kgBw,
                                   kgBb, vw1, vb1, vw2, vb2, vgAw, vgAb, vgBw,
                                   vgBb, Ak, Bk, Av, Bv);
  // conversions
  cvt_bf16<<<(BB * SS * DD / 4) / 256, 256, 0, stream>>>(x, xb);
  cvt_wt<<<dim3(32, 32), 256, 0, stream>>>(Wq, Wtq);
  cvt_wt<<<dim3(32, 32), 256, 0, stream>>>(Wk, Wtk);
  cvt_wt<<<dim3(32, 32), 256, 0, stream>>>(Wv, Wtv);
  cvt_wt<<<dim3(32, 32), 256, 0, stream>>>(Wo, Wto);
  // low-rank coefficients
  xa_kernel<<<BB * SS, 256, 0, stream>>>(x, Ak, Av, xak, xav);

  const int M = BB * SS;
  dim3 ggrid(M / 128, DD / 128);
  int nrp = (BB * SS * DD / 2) / 256;

  // q path
  gemm_bf16<<<ggrid, 256, 0, stream>>>(xb, Wtq, bq, qf, M, DD, DD);
  dyn_rope_pack<<<nrp, 256, 0, stream>>>(qf, nullptr, nullptr, qhb, 1);
  // k path
  gemm_bf16<<<ggrid, 256, 0, stream>>>(xb, Wtk, bk, qf, M, DD, DD);
  dyn_rope_pack<<<nrp, 256, 0, stream>>>(qf, xak, Bk, khb, 1);
  // v path
  gemm_bf16<<<ggrid, 256, 0, stream>>>(xb, Wtv, bv, qf, M, DD, DD);
  dyn_rope_pack<<<nrp, 256, 0, stream>>>(qf, xav, Bv, vhb, 0);

  // attention
  attn_mfma<<<dim3(BB * NH, SS / 64), 256, 0, stream>>>(qhb, khb, vhb, aob);

  // output projection
  gemm_bf16<<<ggrid, 256, 0, stream>>>(aob, Wto, bo, out, M, DD, DD);
}

// Round 3
// 452.337 us; speedup vs baseline: 3.4419x; 1.6280x over previous
//
#include <hip/hip_runtime.h>
#include <math.h>

#define BB 2
#define SS 2048
#define DD 1024
#define NH 16
#define HDM 64
#define RNK 8

typedef short short8 __attribute__((ext_vector_type(8)));
typedef float floatx4 __attribute__((ext_vector_type(4)));

static __device__ __forceinline__ ushort f2bf(float f) {
  union { float f; unsigned u; } v;
  v.f = f;
  unsigned r = (v.u + 0x7FFFu + ((v.u >> 16) & 1u)) >> 16;
  return (ushort)r;
}

// ---------------------------------------------------------------------------
// z-pool: zsum[b][d] += sum over 64 rows of x
// ---------------------------------------------------------------------------
__global__ __launch_bounds__(256) void z_pool(const float* __restrict__ x,
                                              float* __restrict__ zsum) {
  int b = blockIdx.x;
  int s0 = blockIdx.y * 64;
  int tid = threadIdx.x;
  float p0 = 0.f, p1 = 0.f, p2 = 0.f, p3 = 0.f;
  const float* xp = x + ((size_t)b * SS + s0) * DD;
  for (int s = 0; s < 64; ++s) {
    const float* row = xp + (size_t)s * DD;
    p0 += row[tid];
    p1 += row[tid + 256];
    p2 += row[tid + 512];
    p3 += row[tid + 768];
  }
  atomicAdd(&zsum[b * DD + tid], p0);
  atomicAdd(&zsum[b * DD + tid + 256], p1);
  atomicAdd(&zsum[b * DD + tid + 512], p2);
  atomicAdd(&zsum[b * DD + tid + 768], p3);
}

// ---------------------------------------------------------------------------
// hyper_c: z -> h=silu(z@w1+b1) -> c=h@w2+b2  (tiny; 4 blocks)
// c_all layout: [p][b][64]
// ---------------------------------------------------------------------------
__global__ __launch_bounds__(256) void hyper_c(
    const float* __restrict__ zsum,
    const float* __restrict__ kw1, const float* __restrict__ kb1,
    const float* __restrict__ kw2, const float* __restrict__ kb2,
    const float* __restrict__ vw1, const float* __restrict__ vb1,
    const float* __restrict__ vw2, const float* __restrict__ vb2,
    float* __restrict__ c_all) {
  int p = blockIdx.x >> 1;
  int b = blockIdx.x & 1;
  const float* w1 = p ? vw1 : kw1;
  const float* b1 = p ? vb1 : kb1;
  const float* w2 = p ? vw2 : kw2;
  const float* b2 = p ? vb2 : kb2;

  __shared__ float zs[DD];
  __shared__ float hs[256];
  int tid = threadIdx.x;
  for (int d = tid; d < DD; d += 256)
    zs[d] = zsum[b * DD + d] * (1.0f / (float)SS);
  __syncthreads();

  float acc = b1[tid];
#pragma unroll 8
  for (int j = 0; j < DD; ++j) acc += zs[j] * w1[j * 256 + tid];
  hs[tid] = acc / (1.0f + expf(-acc));
  __syncthreads();

  if (tid < 64) {
    float a = b2[tid];
#pragma unroll 8
    for (int j = 0; j < 256; ++j) a += hs[j] * w2[j * 64 + tid];
    c_all[(p * 2 + b) * 64 + tid] = a;
  }
}

// ---------------------------------------------------------------------------
// gen_AB: A/B = c @ gW + gb, parallel over columns. One block = 256 columns
// of one {path, A|B} matrix; each thread does both batches (weight read once).
// grid = (8192/256, 4)  y: 0=K.A 1=K.B 2=V.A 3=V.B
// ---------------------------------------------------------------------------
__global__ __launch_bounds__(256) void gen_AB(
    const float* __restrict__ c_all,
    const float* __restrict__ kgAw, const float* __restrict__ kgAb,
    const float* __restrict__ kgBw, const float* __restrict__ kgBb,
    const float* __restrict__ vgAw, const float* __restrict__ vgAb,
    const float* __restrict__ vgBw, const float* __restrict__ vgBb,
    float* __restrict__ Ak, float* __restrict__ Bk,
    float* __restrict__ Av, float* __restrict__ Bv) {
  int y = blockIdx.y;
  int p = y >> 1, mat = y & 1;
  const float* gw = p ? (mat ? vgBw : vgAw) : (mat ? kgBw : kgAw);
  const float* gb = p ? (mat ? vgBb : vgAb) : (mat ? kgBb : kgAb);
  float* obase = p ? (mat ? Bv : Av) : (mat ? Bk : Ak);

  __shared__ float c0[64], c1[64];
  int tid = threadIdx.x;
  if (tid < 64) c0[tid] = c_all[p * 128 + tid];
  else if (tid < 128) c1[tid - 64] = c_all[p * 128 + tid];
  __syncthreads();

  int idx = blockIdx.x * 256 + tid;
  float a0 = gb[idx], a1 = a0;
#pragma unroll
  for (int j = 0; j < 64; ++j) {
    float w = gw[j * (RNK * DD) + idx];
    a0 += c0[j] * w;
    a1 += c1[j] * w;
  }
  obase[idx] = a0;
  obase[RNK * DD + idx] = a1;
}

// ---------------------------------------------------------------------------
// xa[b,s,r] = dot(x[b,s,:], A[b,r,:]) for both k and v paths
// ---------------------------------------------------------------------------
__global__ __launch_bounds__(256) void xa_kernel(
    const float* __restrict__ x,
    const float* __restrict__ Ak, const float* __restrict__ Av,
    float* __restrict__ xak, float* __restrict__ xav) {
  int bs = blockIdx.x;
  int b = bs >> 11;
  __shared__ float xrow[DD];
  int tid = threadIdx.x;
  ((float4*)xrow)[tid] = ((const float4*)(x + (size_t)bs * DD))[tid];
  __syncthreads();
  int g = tid >> 4;
  int l16 = tid & 15;
  int p = g >> 3;
  int r = g & 7;
  const float* Ar = (p ? Av : Ak) + ((size_t)(b * RNK + r) << 10);
  float acc = 0.f;
  for (int d = l16; d < DD; d += 16) acc += xrow[d] * Ar[d];
#pragma unroll
  for (int off = 8; off; off >>= 1) acc += __shfl_xor(acc, off, 16);
  if (l16 == 0) (p ? xav : xak)[bs * RNK + r] = acc;
}

// ---------------------------------------------------------------------------
// cvt_bf16: fp32 -> bf16, same layout
// ---------------------------------------------------------------------------
__global__ __launch_bounds__(256) void cvt_bf16(const float* __restrict__ in,
                                                ushort* __restrict__ out) {
  int gid = blockIdx.x * 256 + threadIdx.x;
  float4 a = ((const float4*)in)[gid];
  ushort4 o;
  o.x = f2bf(a.x);
  o.y = f2bf(a.y);
  o.z = f2bf(a.z);
  o.w = f2bf(a.w);
  ((ushort4*)out)[gid] = o;
}

// ---------------------------------------------------------------------------
// cvt_wt: W fp32 [K][N] -> Wt bf16 [N][K]
// ---------------------------------------------------------------------------
__global__ __launch_bounds__(256) void cvt_wt(const float* __restrict__ W,
                                              ushort* __restrict__ Wt) {
  __shared__ float tile[32][33];
  int bx = blockIdx.x, by = blockIdx.y;
  int tx = threadIdx.x & 31, ty = threadIdx.x >> 5;
#pragma unroll
  for (int i = 0; i < 4; ++i)
    tile[ty + 8 * i][tx] = W[(size_t)(by * 32 + ty + 8 * i) * DD + bx * 32 + tx];
  __syncthreads();
#pragma unroll
  for (int i = 0; i < 4; ++i)
    Wt[(size_t)(bx * 32 + ty + 8 * i) * DD + by * 32 + tx] =
        f2bf(tile[tx][ty + 8 * i]);
}

// ---------------------------------------------------------------------------
// dyn-add (optional) + RoPE (optional) + pack to bf16 head-major [b][h][s][hd]
// ---------------------------------------------------------------------------
__global__ __launch_bounds__(256) void dyn_rope_pack(
    const float* __restrict__ t, const float* __restrict__ xa,
    const float* __restrict__ Bm, ushort* __restrict__ th, int do_rope) {
  int gid = blockIdx.x * 256 + threadIdx.x;
  int i = gid & 31;
  int h = (gid >> 5) & 15;
  int s = (gid >> 9) & 2047;
  int b = gid >> 20;
  int o1 = h * HDM + i;
  int o2 = o1 + 32;
  size_t base = ((size_t)(b * SS + s)) << 10;
  float v1 = t[base + o1];
  float v2 = t[base + o2];
  if (xa) {
    const float* xr = &xa[(size_t)(b * SS + s) * RNK];
    float4 x0 = *(const float4*)xr;
    float4 x1 = *(const float4*)(xr + 4);
    const float* bp1 = &Bm[(size_t)(b * DD + o1) * RNK];
    float4 A0 = *(const float4*)bp1;
    float4 A1 = *(const float4*)(bp1 + 4);
    const float* bp2 = &Bm[(size_t)(b * DD + o2) * RNK];
    float4 B0 = *(const float4*)bp2;
    float4 B1 = *(const float4*)(bp2 + 4);
    float d1 = x0.x * A0.x + x0.y * A0.y + x0.z * A0.z + x0.w * A0.w +
               x1.x * A1.x + x1.y * A1.y + x1.z * A1.z + x1.w * A1.w;
    float d2 = x0.x * B0.x + x0.y * B0.y + x0.z * B0.z + x0.w * B0.w +
               x1.x * B1.x + x1.y * B1.y + x1.z * B1.z + x1.w * B1.w;
    v1 += d1 * (1.0f / RNK);
    v2 += d2 * (1.0f / RNK);
  }
  if (do_rope) {
    float freq = expf(-(float)i * (9.210340371976184f / 32.0f));
    float ang = (float)s * freq;
    float sn, cn;
    sincosf(ang, &sn, &cn);
    float n1 = v1 * cn - v2 * sn;
    float n2 = v2 * cn + v1 * sn;
    v1 = n1;
    v2 = n2;
  }
  size_t ob = ((size_t)(b * NH + h) * SS + s) * HDM + i;
  th[ob] = f2bf(v1);
  th[ob + 32] = f2bf(v2);
}

// ---------------------------------------------------------------------------
// bf16 MFMA GEMM: C[M][N] = A[M][K] @ Bt[N][K]^T + bias  (C fp32)
// 128x128 tile, BK=32, 4 waves each 64x64
// ---------------------------------------------------------------------------
__global__ __launch_bounds__(256) void gemm_bf16(
    const ushort* __restrict__ A, const ushort* __restrict__ Bt,
    const float* __restrict__ bias, float* __restrict__ C,
    int M, int N, int K) {
  __shared__ ushort As[128][40];
  __shared__ ushort Bs[128][40];
  int tid = threadIdx.x;
  int bm = blockIdx.x * 128, bn = blockIdx.y * 128;
  int w = tid >> 6, lane = tid & 63, l16 = lane & 15, q4 = lane >> 4;
  int wm = (w >> 1) * 64, wn = (w & 1) * 64;
  floatx4 acc[4][4];
#pragma unroll
  for (int mi = 0; mi < 4; ++mi)
#pragma unroll
    for (int ni = 0; ni < 4; ++ni) acc[mi][ni] = 0;

  int sr = tid >> 2, sc = (tid & 3) * 8;
  const ushort* Ap0 = A + (size_t)(bm + sr) * K + sc;
  const ushort* Ap1 = A + (size_t)(bm + sr + 64) * K + sc;
  const ushort* Bp0 = Bt + (size_t)(bn + sr) * K + sc;
  const ushort* Bp1 = Bt + (size_t)(bn + sr + 64) * K + sc;

  for (int k0 = 0; k0 < K; k0 += 32) {
    uint4 a0 = *(const uint4*)(Ap0 + k0);
    uint4 a1 = *(const uint4*)(Ap1 + k0);
    uint4 b0 = *(const uint4*)(Bp0 + k0);
    uint4 b1 = *(const uint4*)(Bp1 + k0);
    __syncthreads();
    *(uint4*)&As[sr][sc] = a0;
    *(uint4*)&As[sr + 64][sc] = a1;
    *(uint4*)&Bs[sr][sc] = b0;
    *(uint4*)&Bs[sr + 64][sc] = b1;
    __syncthreads();
    short8 af[4], bf[4];
#pragma unroll
    for (int mi = 0; mi < 4; ++mi)
      af[mi] = *(const short8*)&As[wm + mi * 16 + l16][q4 * 8];
#pragma unroll
    for (int ni = 0; ni < 4; ++ni)
      bf[ni] = *(const short8*)&Bs[wn + ni * 16 + l16][q4 * 8];
#pragma unroll
    for (int mi = 0; mi < 4; ++mi)
#pragma unroll
      for (int ni = 0; ni < 4; ++ni)
        acc[mi][ni] = __builtin_amdgcn_mfma_f32_16x16x32_bf16(
            af[mi], bf[ni], acc[mi][ni], 0, 0, 0);
  }
#pragma unroll
  for (int mi = 0; mi < 4; ++mi) {
#pragma unroll
    for (int r = 0; r < 4; ++r) {
      int row = bm + wm + mi * 16 + q4 * 4 + r;
      float* Cr = C + (size_t)row * N;
#pragma unroll
      for (int ni = 0; ni < 4; ++ni) {
        int col = bn + wn + ni * 16 + l16;
        Cr[col] = acc[mi][ni][r] + bias[col];
      }
    }
  }
}

// ---------------------------------------------------------------------------
// MFMA flash attention (causal). Block = (b,h) x 64-query tile, 4 waves.
// ---------------------------------------------------------------------------
#define VT_IDX(d, c) ((unsigned)(72 * (d) + 16 * ((d) >> 3) + (c)))

__global__ __launch_bounds__(256) void attn_mfma(
    const ushort* __restrict__ qh, const ushort* __restrict__ kh,
    const ushort* __restrict__ vh, ushort* __restrict__ ao) {
  __shared__ ushort Ks[64][72];
  __shared__ ushort Vt[4720];
  __shared__ ushort Ps[64][72];
  int bh = blockIdx.x;
  int b = bh >> 4, h = bh & 15;
  int q0 = blockIdx.y * 64;
  int tid = threadIdx.x;
  int w = tid >> 6, lane = tid & 63, l16 = lane & 15, q4 = lane >> 4;

  const ushort* qrow =
      qh + ((size_t)bh * SS + q0 + 16 * w + l16) * HDM;
  short8 qf0 = *(const short8*)(qrow + q4 * 8);
  short8 qf1 = *(const short8*)(qrow + 32 + q4 * 8);

  floatx4 o[4];
#pragma unroll
  for (int ni = 0; ni < 4; ++ni) o[ni] = 0;
  float m_r[4], l_r[4];
#pragma unroll
  for (int r = 0; r < 4; ++r) {
    m_r[r] = -1e30f;
    l_r[r] = 0.f;
  }

  int nkt = (q0 >> 6) + 1;
  int skr = tid >> 2, skc = (tid & 3) * 8;
  int so8 = tid & 7, sp = tid >> 3;
  const ushort* kbase = kh + (size_t)bh * SS * HDM;
  const ushort* vbase = vh + (size_t)bh * SS * HDM;

  for (int kt = 0; kt < nkt; ++kt) {
    int k0 = kt * 64;
    __syncthreads();
    *(uint4*)&Ks[skr][skc] =
        *(const uint4*)(kbase + (size_t)(k0 + skr) * HDM + skc);
    *(uint4*)&Ks[skr][skc + 32] =
        *(const uint4*)(kbase + (size_t)(k0 + skr) * HDM + skc + 32);
    const ushort* v0 = vbase + (size_t)(k0 + 2 * sp) * HDM + so8 * 8;
    uint4 va = *(const uint4*)v0;
    uint4 vb = *(const uint4*)(v0 + HDM);
    const ushort* pa = (const ushort*)&va;
    const ushort* pb = (const ushort*)&vb;
#pragma unroll
    for (int j = 0; j < 8; ++j) {
      int d = so8 * 8 + j;
      *(unsigned*)&Vt[VT_IDX(d, 2 * sp)] =
          (unsigned)pa[j] | ((unsigned)pb[j] << 16);
    }
    __syncthreads();

    floatx4 s4[4];
#pragma unroll
    for (int ni = 0; ni < 4; ++ni) {
      short8 kf0 = *(const short8*)&Ks[ni * 16 + l16][q4 * 8];
      short8 kf1 = *(const short8*)&Ks[ni * 16 + l16][32 + q4 * 8];
      floatx4 c;
      c = 0;
      c = __builtin_amdgcn_mfma_f32_16x16x32_bf16(qf0, kf0, c, 0, 0, 0);
      c = __builtin_amdgcn_mfma_f32_16x16x32_bf16(qf1, kf1, c, 0, 0, 0);
      s4[ni] = c;
    }

    bool diag = (kt == nkt - 1);
    float sv[4][4];
#pragma unroll
    for (int ni = 0; ni < 4; ++ni) {
#pragma unroll
      for (int r = 0; r < 4; ++r) {
        float vvv = s4[ni][r] * 0.125f;
        if (diag) {
          int key = k0 + ni * 16 + l16;
          int qr = q0 + 16 * w + q4 * 4 + r;
          if (key > qr) vvv = -1e30f;
        }
        sv[ni][r] = vvv;
      }
    }
    float alpha[4];
#pragma unroll
    for (int r = 0; r < 4; ++r) {
      float mloc = fmaxf(fmaxf(sv[0][r], sv[1][r]), fmaxf(sv[2][r], sv[3][r]));
      mloc = fmaxf(mloc, __shfl_xor(mloc, 1));
      mloc = fmaxf(mloc, __shfl_xor(mloc, 2));
      mloc = fmaxf(mloc, __shfl_xor(mloc, 4));
      mloc = fmaxf(mloc, __shfl_xor(mloc, 8));
      float mn = fmaxf(m_r[r], mloc);
      alpha[r] = __expf(m_r[r] - mn);
      m_r[r] = mn;
      float ps = 0.f;
      int prow = 16 * w + q4 * 4 + r;
#pragma unroll
      for (int ni = 0; ni < 4; ++ni) {
        float p = __expf(sv[ni][r] - mn);
        Ps[prow][ni * 16 + l16] = f2bf(p);
        ps += p;
      }
      ps += __shfl_xor(ps, 1);
      ps += __shfl_xor(ps, 2);
      ps += __shfl_xor(ps, 4);
      ps += __shfl_xor(ps, 8);
      l_r[r] = l_r[r] * alpha[r] + ps;
#pragma unroll
      for (int ni = 0; ni < 4; ++ni) o[ni][r] *= alpha[r];
    }

    short8 pf0 = *(const short8*)&Ps[16 * w + l16][q4 * 8];
    short8 pf1 = *(const short8*)&Ps[16 * w + l16][32 + q4 * 8];
#pragma unroll
    for (int ni = 0; ni < 4; ++ni) {
      short8 vf0 = *(const short8*)&Vt[VT_IDX(ni * 16 + l16, q4 * 8)];
      short8 vf1 = *(const short8*)&Vt[VT_IDX(ni * 16 + l16, 32 + q4 * 8)];
      o[ni] = __builtin_amdgcn_mfma_f32_16x16x32_bf16(pf0, vf0, o[ni], 0, 0, 0);
      o[ni] = __builtin_amdgcn_mfma_f32_16x16x32_bf16(pf1, vf1, o[ni], 0, 0, 0);
    }
  }

#pragma unroll
  for (int r = 0; r < 4; ++r) {
    float inv = 1.0f / l_r[r];
    int srow = q0 + 16 * w + q4 * 4 + r;
    ushort* orow = ao + ((size_t)b * SS + srow) * DD + h * HDM;
#pragma unroll
    for (int ni = 0; ni < 4; ++ni) orow[ni * 16 + l16] = f2bf(o[ni][r] * inv);
  }
}

// ---------------------------------------------------------------------------
extern "C" void kernel_launch(void* const* d_in, const int* in_sizes, int n_in,
                              void* d_out, int out_size, void* d_ws,
                              size_t ws_size, hipStream_t stream) {
  const float* x    = (const float*)d_in[0];
  const float* Wq   = (const float*)d_in[1];
  const float* bq   = (const float*)d_in[2];
  const float* Wo   = (const float*)d_in[3];
  const float* bo   = (const float*)d_in[4];
  const float* Wk   = (const float*)d_in[5];
  const float* bk   = (const float*)d_in[6];
  const float* kw1  = (const float*)d_in[7];
  const float* kb1  = (const float*)d_in[8];
  const float* kw2  = (const float*)d_in[9];
  const float* kb2  = (const float*)d_in[10];
  const float* kgAw = (const float*)d_in[11];
  const float* kgAb = (const float*)d_in[12];
  const float* kgBw = (const float*)d_in[13];
  const float* kgBb = (const float*)d_in[14];
  const float* Wv   = (const float*)d_in[15];
  const float* bv   = (const float*)d_in[16];
  const float* vw1  = (const float*)d_in[17];
  const float* vb1  = (const float*)d_in[18];
  const float* vw2  = (const float*)d_in[19];
  const float* vb2  = (const float*)d_in[20];
  const float* vgAw = (const float*)d_in[21];
  const float* vgAb = (const float*)d_in[22];
  const float* vgBw = (const float*)d_in[23];
  const float* vgBb = (const float*)d_in[24];
  float* out = (float*)d_out;

  char* ws = (char*)d_ws;
  const size_t MB = 1024 * 1024;
  float*  qf  = (float*)(ws);            // 16 MB fp32 scratch (q,k,v serially)
  ushort* aob = (ushort*)(ws);           // attn out bf16, aliases qf (dead)
  ushort* qhb = (ushort*)(ws + 16 * MB);
  ushort* khb = (ushort*)(ws + 24 * MB);
  ushort* vhb = (ushort*)(ws + 32 * MB);
  ushort* xb  = (ushort*)(ws + 40 * MB);
  ushort* Wtq = (ushort*)(ws + 48 * MB);
  ushort* Wtk = (ushort*)(ws + 50 * MB);
  ushort* Wtv = (ushort*)(ws + 52 * MB);
  ushort* Wto = (ushort*)(ws + 54 * MB);
  float*  Ak  = (float*)(ws + 56 * MB);
  float*  Bk  = Ak + BB * RNK * DD;
  float*  Av  = Bk + BB * DD * RNK;
  float*  Bv  = Av + BB * RNK * DD;
  float*  xak = Bv + BB * DD * RNK;
  float*  xav = xak + BB * SS * RNK;
  float*  zsum = xav + BB * SS * RNK;
  float*  c_all = zsum + BB * DD;

  hipMemsetAsync(zsum, 0, BB * DD * sizeof(float), stream);
  z_pool<<<dim3(BB, SS / 64), 256, 0, stream>>>(x, zsum);
  hyper_c<<<4, 256, 0, stream>>>(zsum, kw1, kb1, kw2, kb2, vw1, vb1, vw2, vb2,
                                 c_all);
  gen_AB<<<dim3(RNK * DD / 256, 4), 256, 0, stream>>>(
      c_all, kgAw, kgAb, kgBw, kgBb, vgAw, vgAb, vgBw, vgBb, Ak, Bk, Av, Bv);
  // conversions
  cvt_bf16<<<(BB * SS * DD / 4) / 256, 256, 0, stream>>>(x, xb);
  cvt_wt<<<dim3(32, 32), 256, 0, stream>>>(Wq, Wtq);
  cvt_wt<<<dim3(32, 32), 256, 0, stream>>>(Wk, Wtk);
  cvt_wt<<<dim3(32, 32), 256, 0, stream>>>(Wv, Wtv);
  cvt_wt<<<dim3(32, 32), 256, 0, stream>>>(Wo, Wto);
  // low-rank coefficients
  xa_kernel<<<BB * SS, 256, 0, stream>>>(x, Ak, Av, xak, xav);

  const int M = BB * SS;
  dim3 ggrid(M / 128, DD / 128);
  int nrp = (BB * SS * DD / 2) / 256;

  // q path
  gemm_bf16<<<ggrid, 256, 0, stream>>>(xb, Wtq, bq, qf, M, DD, DD);
  dyn_rope_pack<<<nrp, 256, 0, stream>>>(qf, nullptr, nullptr, qhb, 1);
  // k path
  gemm_bf16<<<ggrid, 256, 0, stream>>>(xb, Wtk, bk, qf, M, DD, DD);
  dyn_rope_pack<<<nrp, 256, 0, stream>>>(qf, xak, Bk, khb, 1);
  // v path
  gemm_bf16<<<ggrid, 256, 0, stream>>>(xb, Wtv, bv, qf, M, DD, DD);
  dyn_rope_pack<<<nrp, 256, 0, stream>>>(qf, xav, Bv, vhb, 0);

  // attention
  attn_mfma<<<dim3(BB * NH, SS / 64), 256, 0, stream>>>(qhb, khb, vhb, aob);

  // output projection
  gemm_bf16<<<ggrid, 256, 0, stream>>>(aob, Wto, bo, out, M, DD, DD);
}

// Round 4
// 335.447 us; speedup vs baseline: 4.6413x; 1.3485x over previous
//
#include <hip/hip_runtime.h>
#include <math.h>

#define BB 2
#define SS 2048
#define DD 1024
#define NH 16
#define HDM 64
#define RNK 8

typedef short short8 __attribute__((ext_vector_type(8)));
typedef float floatx4 __attribute__((ext_vector_type(4)));

static __device__ __forceinline__ ushort f2bf(float f) {
  union { float f; unsigned u; } v;
  v.f = f;
  unsigned r = (v.u + 0x7FFFu + ((v.u >> 16) & 1u)) >> 16;
  return (ushort)r;
}
static __device__ __forceinline__ float bf2f(ushort u) {
  union { unsigned u; float f; } v;
  v.u = ((unsigned)u) << 16;
  return v.f;
}

// ---------------------------------------------------------------------------
// z-pool: zsum[b][d] += sum over 16 rows of x  (256 blocks)
// ---------------------------------------------------------------------------
__global__ __launch_bounds__(256) void z_pool(const float* __restrict__ x,
                                              float* __restrict__ zsum) {
  int b = blockIdx.x;
  int s0 = blockIdx.y * 16;
  int tid = threadIdx.x;
  float p0 = 0.f, p1 = 0.f, p2 = 0.f, p3 = 0.f;
  const float* xp = x + ((size_t)b * SS + s0) * DD;
  for (int s = 0; s < 16; ++s) {
    const float* row = xp + (size_t)s * DD;
    p0 += row[tid];
    p1 += row[tid + 256];
    p2 += row[tid + 512];
    p3 += row[tid + 768];
  }
  atomicAdd(&zsum[b * DD + tid], p0);
  atomicAdd(&zsum[b * DD + tid + 256], p1);
  atomicAdd(&zsum[b * DD + tid + 512], p2);
  atomicAdd(&zsum[b * DD + tid + 768], p3);
}

// ---------------------------------------------------------------------------
// gen_h: h_pre[b][n] += sum over 64-row slice of z[j]*w1[j][n]  (32 blocks)
// ---------------------------------------------------------------------------
__global__ __launch_bounds__(256) void gen_h(
    const float* __restrict__ zsum,
    const float* __restrict__ kw1, const float* __restrict__ vw1,
    float* __restrict__ h_pre) {
  int b = blockIdx.x & 1;
  int p = (blockIdx.x >> 1) & 1;
  int slice = blockIdx.y;
  const float* w1 = p ? vw1 : kw1;
  int tid = threadIdx.x;
  float acc = 0.f;
  int j0 = slice * 128;
  for (int j = j0; j < j0 + 128; ++j) {
    float z = zsum[b * DD + j] * (1.0f / (float)SS);
    acc += z * w1[j * 256 + tid];
  }
  atomicAdd(&h_pre[(p * 2 + b) * 256 + tid], acc);
}

// ---------------------------------------------------------------------------
// hyper_c2: c = silu(h_pre + b1) @ w2 + b2   (4 blocks)
// ---------------------------------------------------------------------------
__global__ __launch_bounds__(256) void hyper_c2(
    const float* __restrict__ h_pre,
    const float* __restrict__ kb1, const float* __restrict__ kw2,
    const float* __restrict__ kb2,
    const float* __restrict__ vb1, const float* __restrict__ vw2,
    const float* __restrict__ vb2, float* __restrict__ c_all) {
  int p = blockIdx.x >> 1;
  int b = blockIdx.x & 1;
  const float* b1 = p ? vb1 : kb1;
  const float* w2 = p ? vw2 : kw2;
  const float* b2 = p ? vb2 : kb2;
  __shared__ float hs[256];
  __shared__ float part[256];
  int tid = threadIdx.x;
  float hv = h_pre[(p * 2 + b) * 256 + tid] + b1[tid];
  hs[tid] = hv / (1.0f + expf(-hv));
  __syncthreads();
  int n = tid & 63, chunk = tid >> 6;
  float a = 0.f;
  for (int jj = 0; jj < 64; ++jj) {
    int j = chunk * 64 + jj;
    a += hs[j] * w2[j * 64 + n];
  }
  part[tid] = a;
  __syncthreads();
  if (tid < 64) {
    c_all[(p * 2 + b) * 64 + tid] =
        part[tid] + part[tid + 64] + part[tid + 128] + part[tid + 192] + b2[tid];
  }
}

// ---------------------------------------------------------------------------
// gen_AB: A/B = c @ gW + gb  (128 x 4 blocks)
// ---------------------------------------------------------------------------
__global__ __launch_bounds__(256) void gen_AB(
    const float* __restrict__ c_all,
    const float* __restrict__ kgAw, const float* __restrict__ kgAb,
    const float* __restrict__ kgBw, const float* __restrict__ kgBb,
    const float* __restrict__ vgAw, const float* __restrict__ vgAb,
    const float* __restrict__ vgBw, const float* __restrict__ vgBb,
    float* __restrict__ Ak, float* __restrict__ Bk,
    float* __restrict__ Av, float* __restrict__ Bv) {
  int y = blockIdx.y;
  int p = y >> 1, mat = y & 1;
  const float* gw = p ? (mat ? vgBw : vgAw) : (mat ? kgBw : kgAw);
  const float* gb = p ? (mat ? vgBb : vgAb) : (mat ? kgBb : kgAb);
  float* obase = p ? (mat ? Bv : Av) : (mat ? Bk : Ak);

  __shared__ float c0[64], c1[64];
  int tid = threadIdx.x;
  if (tid < 64) c0[tid] = c_all[p * 128 + tid];
  else if (tid < 128) c1[tid - 64] = c_all[p * 128 + tid];
  __syncthreads();

  int idx = blockIdx.x * 256 + tid;
  float a0 = gb[idx], a1 = a0;
#pragma unroll
  for (int j = 0; j < 64; ++j) {
    float w = gw[j * (RNK * DD) + idx];
    a0 += c0[j] * w;
    a1 += c1[j] * w;
  }
  obase[idx] = a0;
  obase[RNK * DD + idx] = a1;
}

// ---------------------------------------------------------------------------
// cvt_bf16: fp32 -> bf16
// ---------------------------------------------------------------------------
__global__ __launch_bounds__(256) void cvt_bf16(const float* __restrict__ in,
                                                ushort* __restrict__ out) {
  int gid = blockIdx.x * 256 + threadIdx.x;
  float4 a = ((const float4*)in)[gid];
  ushort4 o;
  o.x = f2bf(a.x);
  o.y = f2bf(a.y);
  o.z = f2bf(a.z);
  o.w = f2bf(a.w);
  ((ushort4*)out)[gid] = o;
}

// ---------------------------------------------------------------------------
// cvt_wt: W fp32 [K][N] -> Wt bf16 [N][K]
// ---------------------------------------------------------------------------
__global__ __launch_bounds__(256) void cvt_wt(const float* __restrict__ W,
                                              ushort* __restrict__ Wt) {
  __shared__ float tile[32][33];
  int bx = blockIdx.x, by = blockIdx.y;
  int tx = threadIdx.x & 31, ty = threadIdx.x >> 5;
#pragma unroll
  for (int i = 0; i < 4; ++i)
    tile[ty + 8 * i][tx] = W[(size_t)(by * 32 + ty + 8 * i) * DD + bx * 32 + tx];
  __syncthreads();
#pragma unroll
  for (int i = 0; i < 4; ++i)
    Wt[(size_t)(bx * 32 + ty + 8 * i) * DD + by * 32 + tx] =
        f2bf(tile[tx][ty + 8 * i]);
}

// ---------------------------------------------------------------------------
// rope_tab: tab[i][s] = (cos(s*f_i), sin(s*f_i)), i in [0,32), s in [0,2048)
// ---------------------------------------------------------------------------
__global__ __launch_bounds__(256) void rope_tab(float2* __restrict__ tab) {
  int gid = blockIdx.x * 256 + threadIdx.x;
  int i = gid >> 11, s = gid & 2047;
  float freq = expf(-(float)i * (9.210340371976184f / 32.0f));
  float sn, cn;
  sincosf((float)s * freq, &sn, &cn);
  tab[gid] = make_float2(cn, sn);
}

// ---------------------------------------------------------------------------
// weff: Wcat[1+2p+b][n][kk] = Wt[n][kk] + (1/8) sum_r Bm[n][r] * A[r][kk]
// grid (64, 4): 16 rows per block
// ---------------------------------------------------------------------------
__global__ __launch_bounds__(256) void weff(
    const float* __restrict__ Ak, const float* __restrict__ Bk,
    const float* __restrict__ Av, const float* __restrict__ Bv,
    const ushort* __restrict__ Wtk, const ushort* __restrict__ Wtv,
    ushort* __restrict__ Wcat) {
  int y = blockIdx.y;
  int p = y >> 1, b = y & 1;
  const float* A = (p ? Av : Ak) + b * (RNK * DD);
  const float* Bm = (p ? Bv : Bk) + b * (RNK * DD);
  const ushort* src = p ? Wtv : Wtk;
  ushort* dst = Wcat + ((size_t)(1 + 2 * p + b) << 20);

  int tid = threadIdx.x;
  int row = blockIdx.x * 16 + (tid >> 4);
  int cg = tid & 15;
  float bm[RNK];
#pragma unroll
  for (int r = 0; r < RNK; ++r) bm[r] = Bm[row * RNK + r];
  for (int kk = cg * 64; kk < cg * 64 + 64; kk += 4) {
    float4 acc = make_float4(0.f, 0.f, 0.f, 0.f);
#pragma unroll
    for (int r = 0; r < RNK; ++r) {
      float4 a4 = *(const float4*)&A[r * DD + kk];
      acc.x += bm[r] * a4.x;
      acc.y += bm[r] * a4.y;
      acc.z += bm[r] * a4.z;
      acc.w += bm[r] * a4.w;
    }
    ushort4 ws = *(const ushort4*)&src[(size_t)row * DD + kk];
    ushort4 o;
    o.x = f2bf(bf2f(ws.x) + acc.x * 0.125f);
    o.y = f2bf(bf2f(ws.y) + acc.y * 0.125f);
    o.z = f2bf(bf2f(ws.z) + acc.z * 0.125f);
    o.w = f2bf(bf2f(ws.w) + acc.w * 0.125f);
    *(ushort4*)&dst[(size_t)row * DD + kk] = o;
  }
}

// ---------------------------------------------------------------------------
// gemm_qkv: fused q/k/v projection. grid (32, 24). ny: 0-7 q, 8-15 k, 16-23 v.
// C = xb @ Wsel^T + bias; epilogue RoPE (q,k) via table; writes bf16
// head-major [b][h][s][64].
// ---------------------------------------------------------------------------
__global__ __launch_bounds__(256) void gemm_qkv(
    const ushort* __restrict__ Axb, const ushort* __restrict__ Wcat,
    const float* __restrict__ bq, const float* __restrict__ bk,
    const float* __restrict__ bv, const float2* __restrict__ tab,
    ushort* __restrict__ qhb, ushort* __restrict__ khb,
    ushort* __restrict__ vhb) {
  __shared__ ushort As[128][40];
  __shared__ ushort Bs[128][40];
  int tid = threadIdx.x;
  int bm = blockIdx.x * 128;
  int ny = blockIdx.y;
  int path = ny >> 3;
  int nb = (ny & 7) * 128;
  int b_blk = bm >> 11;
  const ushort* Wbase =
      (path == 0) ? Wcat : Wcat + ((size_t)(1 + (path - 1) * 2 + b_blk) << 20);
  const float* bias = (path == 0) ? bq : (path == 1 ? bk : bv);
  ushort* outp = (path == 0) ? qhb : (path == 1 ? khb : vhb);

  int w = tid >> 6, lane = tid & 63, l16 = lane & 15, q4 = lane >> 4;
  int wm = (w >> 1) * 64, wn = (w & 1) * 64;
  floatx4 acc[4][4];
#pragma unroll
  for (int mi = 0; mi < 4; ++mi)
#pragma unroll
    for (int ni = 0; ni < 4; ++ni) acc[mi][ni] = 0;

  int sr = tid >> 2, sc = (tid & 3) * 8;
  const ushort* Ap0 = Axb + (size_t)(bm + sr) * DD + sc;
  const ushort* Ap1 = Axb + (size_t)(bm + sr + 64) * DD + sc;
  const ushort* Bp0 = Wbase + (size_t)(nb + sr) * DD + sc;
  const ushort* Bp1 = Wbase + (size_t)(nb + sr + 64) * DD + sc;

  for (int k0 = 0; k0 < DD; k0 += 32) {
    uint4 a0 = *(const uint4*)(Ap0 + k0);
    uint4 a1 = *(const uint4*)(Ap1 + k0);
    uint4 b0 = *(const uint4*)(Bp0 + k0);
    uint4 b1 = *(const uint4*)(Bp1 + k0);
    __syncthreads();
    *(uint4*)&As[sr][sc] = a0;
    *(uint4*)&As[sr + 64][sc] = a1;
    *(uint4*)&Bs[sr][sc] = b0;
    *(uint4*)&Bs[sr + 64][sc] = b1;
    __syncthreads();
    short8 af[4], bf[4];
#pragma unroll
    for (int mi = 0; mi < 4; ++mi)
      af[mi] = *(const short8*)&As[wm + mi * 16 + l16][q4 * 8];
#pragma unroll
    for (int ni = 0; ni < 4; ++ni)
      bf[ni] = *(const short8*)&Bs[wn + ni * 16 + l16][q4 * 8];
#pragma unroll
    for (int mi = 0; mi < 4; ++mi)
#pragma unroll
      for (int ni = 0; ni < 4; ++ni)
        acc[mi][ni] = __builtin_amdgcn_mfma_f32_16x16x32_bf16(
            af[mi], bf[ni], acc[mi][ni], 0, 0, 0);
  }

  int h = (nb + wn) >> 6;
  float biasv[4];
#pragma unroll
  for (int ni = 0; ni < 4; ++ni) biasv[ni] = bias[nb + wn + ni * 16 + l16];

#pragma unroll
  for (int mi = 0; mi < 4; ++mi) {
#pragma unroll
    for (int r = 0; r < 4; ++r) {
      int grow = bm + wm + mi * 16 + q4 * 4 + r;
      int bb = grow >> 11, s = grow & 2047;
      ushort* orow = outp + (((size_t)(bb * NH + h) * SS + s) << 6);
      float v[4];
#pragma unroll
      for (int ni = 0; ni < 4; ++ni) v[ni] = acc[mi][ni][r] + biasv[ni];
      if (path < 2) {
#pragma unroll
        for (int ni = 0; ni < 2; ++ni) {
          float2 cs = tab[((ni * 16 + l16) << 11) + s];
          float a = v[ni] * cs.x - v[ni + 2] * cs.y;
          float c = v[ni + 2] * cs.x + v[ni] * cs.y;
          v[ni] = a;
          v[ni + 2] = c;
        }
      }
#pragma unroll
      for (int ni = 0; ni < 4; ++ni) orow[ni * 16 + l16] = f2bf(v[ni]);
    }
  }
}

// ---------------------------------------------------------------------------
// attn_mfma2: causal flash attention, no-max softmax (shift-invariant; scores
// bounded << 88 so exp cannot overflow). Block = 128 queries (4 waves x 32q),
// 64-key tiles. Heavy (high-q0) blocks launch first. Out: bf16 [b][s][1024].
// ---------------------------------------------------------------------------
#define VT_IDX(d, c) ((unsigned)(72 * (d) + 16 * ((d) >> 3) + (c)))

__global__ __launch_bounds__(256) void attn_mfma2(
    const ushort* __restrict__ qh, const ushort* __restrict__ kh,
    const ushort* __restrict__ vh, ushort* __restrict__ ao) {
  __shared__ ushort Ks[64][72];
  __shared__ ushort Vt[4720];
  __shared__ ushort Ps[128][72];
  int bid = blockIdx.x;
  int bh = bid & 31;
  int q0 = (15 - (bid >> 5)) * 128;  // heavy-first
  int b = bh >> 4, h = bh & 15;
  int tid = threadIdx.x;
  int w = tid >> 6, lane = tid & 63, l16 = lane & 15, q4 = lane >> 4;

  short8 qf[2][2];
#pragma unroll
  for (int mi = 0; mi < 2; ++mi) {
    const ushort* qrow =
        qh + ((size_t)bh * SS + q0 + 32 * w + mi * 16 + l16) * HDM;
    qf[mi][0] = *(const short8*)(qrow + q4 * 8);
    qf[mi][1] = *(const short8*)(qrow + 32 + q4 * 8);
  }

  floatx4 o[2][4];
#pragma unroll
  for (int mi = 0; mi < 2; ++mi)
#pragma unroll
    for (int ni = 0; ni < 4; ++ni) o[mi][ni] = 0;
  float l_part[2][4] = {};

  int nkt = (q0 >> 6) + 2;
  int skr = tid >> 2, skc = (tid & 3) * 8;
  int so8 = tid & 7, sp = tid >> 3;
  const ushort* kbase = kh + (size_t)bh * SS * HDM;
  const ushort* vbase = vh + (size_t)bh * SS * HDM;

  for (int kt = 0; kt < nkt; ++kt) {
    int k0 = kt * 64;
    __syncthreads();
    *(uint4*)&Ks[skr][skc] =
        *(const uint4*)(kbase + (size_t)(k0 + skr) * HDM + skc);
    *(uint4*)&Ks[skr][skc + 32] =
        *(const uint4*)(kbase + (size_t)(k0 + skr) * HDM + skc + 32);
    const ushort* v0 = vbase + (size_t)(k0 + 2 * sp) * HDM + so8 * 8;
    uint4 va = *(const uint4*)v0;
    uint4 vb = *(const uint4*)(v0 + HDM);
    const ushort* pa = (const ushort*)&va;
    const ushort* pb = (const ushort*)&vb;
#pragma unroll
    for (int j = 0; j < 8; ++j) {
      int d = so8 * 8 + j;
      *(unsigned*)&Vt[VT_IDX(d, 2 * sp)] =
          (unsigned)pa[j] | ((unsigned)pb[j] << 16);
    }
    __syncthreads();

    // QK^T: 32 queries x 64 keys per wave
    floatx4 s4[2][4];
#pragma unroll
    for (int ni = 0; ni < 4; ++ni) {
      short8 kf0 = *(const short8*)&Ks[ni * 16 + l16][q4 * 8];
      short8 kf1 = *(const short8*)&Ks[ni * 16 + l16][32 + q4 * 8];
#pragma unroll
      for (int mi = 0; mi < 2; ++mi) {
        floatx4 c;
        c = 0;
        c = __builtin_amdgcn_mfma_f32_16x16x32_bf16(qf[mi][0], kf0, c, 0, 0, 0);
        c = __builtin_amdgcn_mfma_f32_16x16x32_bf16(qf[mi][1], kf1, c, 0, 0, 0);
        s4[mi][ni] = c;
      }
    }

    // no-max softmax: p = exp(s/8); l accumulated per-lane
    bool diag = (kt >= nkt - 2);
#pragma unroll
    for (int mi = 0; mi < 2; ++mi) {
#pragma unroll
      for (int r = 0; r < 4; ++r) {
        int qg = q0 + 32 * w + mi * 16 + q4 * 4 + r;
        int prow = 32 * w + mi * 16 + q4 * 4 + r;
        float lp = 0.f;
#pragma unroll
        for (int ni = 0; ni < 4; ++ni) {
          float t = s4[mi][ni][r] * 0.18033688f;  // 0.125 * log2(e)
          if (diag && (k0 + ni * 16 + l16) > qg) t = -1e38f;
          float p = exp2f(t);
          lp += p;
          Ps[prow][ni * 16 + l16] = f2bf(p);
        }
        l_part[mi][r] += lp;
      }
    }

    // PV
    short8 pf[2][2];
#pragma unroll
    for (int mi = 0; mi < 2; ++mi) {
      pf[mi][0] = *(const short8*)&Ps[32 * w + mi * 16 + l16][q4 * 8];
      pf[mi][1] = *(const short8*)&Ps[32 * w + mi * 16 + l16][32 + q4 * 8];
    }
#pragma unroll
    for (int ni = 0; ni < 4; ++ni) {
      short8 vf0 = *(const short8*)&Vt[VT_IDX(ni * 16 + l16, q4 * 8)];
      short8 vf1 = *(const short8*)&Vt[VT_IDX(ni * 16 + l16, 32 + q4 * 8)];
#pragma unroll
      for (int mi = 0; mi < 2; ++mi) {
        o[mi][ni] =
            __builtin_amdgcn_mfma_f32_16x16x32_bf16(pf[mi][0], vf0, o[mi][ni], 0, 0, 0);
        o[mi][ni] =
            __builtin_amdgcn_mfma_f32_16x16x32_bf16(pf[mi][1], vf1, o[mi][ni], 0, 0, 0);
      }
    }
  }

  // final: reduce l across the 16 key-lanes, normalize, store token-major
#pragma unroll
  for (int mi = 0; mi < 2; ++mi) {
#pragma unroll
    for (int r = 0; r < 4; ++r) {
      float l = l_part[mi][r];
      l += __shfl_xor(l, 1);
      l += __shfl_xor(l, 2);
      l += __shfl_xor(l, 4);
      l += __shfl_xor(l, 8);
      float inv = 1.0f / l;
      int token = q0 + 32 * w + mi * 16 + q4 * 4 + r;
      ushort* orow = ao + ((size_t)(b * SS + token)) * DD + h * HDM;
#pragma unroll
      for (int ni = 0; ni < 4; ++ni)
        orow[ni * 16 + l16] = f2bf(o[mi][ni][r] * inv);
    }
  }
}

// ---------------------------------------------------------------------------
// gemm_out: C[M][N] fp32 = A bf16 @ Wt^T + bias. 64x128 tile, grid (64, 8).
// ---------------------------------------------------------------------------
__global__ __launch_bounds__(256) void gemm_out(
    const ushort* __restrict__ A, const ushort* __restrict__ Bt,
    const float* __restrict__ bias, float* __restrict__ C) {
  __shared__ ushort As[64][40];
  __shared__ ushort Bs[128][40];
  int tid = threadIdx.x;
  int bm = blockIdx.x * 64, bn = blockIdx.y * 128;
  int w = tid >> 6, lane = tid & 63, l16 = lane & 15, q4 = lane >> 4;
  int wm = (w >> 1) * 32, wn = (w & 1) * 64;
  floatx4 acc[2][4];
#pragma unroll
  for (int mi = 0; mi < 2; ++mi)
#pragma unroll
    for (int ni = 0; ni < 4; ++ni) acc[mi][ni] = 0;

  int sr = tid >> 2, sc = (tid & 3) * 8;
  const ushort* Ap0 = A + (size_t)(bm + sr) * DD + sc;
  const ushort* Bp0 = Bt + (size_t)(bn + sr) * DD + sc;
  const ushort* Bp1 = Bt + (size_t)(bn + sr + 64) * DD + sc;

  for (int k0 = 0; k0 < DD; k0 += 32) {
    uint4 a0 = *(const uint4*)(Ap0 + k0);
    uint4 b0 = *(const uint4*)(Bp0 + k0);
    uint4 b1 = *(const uint4*)(Bp1 + k0);
    __syncthreads();
    *(uint4*)&As[sr & 63][sc] = a0;  // sr<64 since 64 rows: tid>>2 in 0..63
    *(uint4*)&Bs[sr][sc] = b0;
    *(uint4*)&Bs[sr + 64][sc] = b1;
    __syncthreads();
    short8 af[2], bf[4];
#pragma unroll
    for (int mi = 0; mi < 2; ++mi)
      af[mi] = *(const short8*)&As[wm + mi * 16 + l16][q4 * 8];
#pragma unroll
    for (int ni = 0; ni < 4; ++ni)
      bf[ni] = *(const short8*)&Bs[wn + ni * 16 + l16][q4 * 8];
#pragma unroll
    for (int mi = 0; mi < 2; ++mi)
#pragma unroll
      for (int ni = 0; ni < 4; ++ni)
        acc[mi][ni] = __builtin_amdgcn_mfma_f32_16x16x32_bf16(
            af[mi], bf[ni], acc[mi][ni], 0, 0, 0);
  }
#pragma unroll
  for (int mi = 0; mi < 2; ++mi) {
#pragma unroll
    for (int r = 0; r < 4; ++r) {
      int row = bm + wm + mi * 16 + q4 * 4 + r;
      float* Cr = C + (size_t)row * DD;
#pragma unroll
      for (int ni = 0; ni < 4; ++ni) {
        int col = bn + wn + ni * 16 + l16;
        Cr[col] = acc[mi][ni][r] + bias[col];
      }
    }
  }
}

// ---------------------------------------------------------------------------
extern "C" void kernel_launch(void* const* d_in, const int* in_sizes, int n_in,
                              void* d_out, int out_size, void* d_ws,
                              size_t ws_size, hipStream_t stream) {
  const float* x    = (const float*)d_in[0];
  const float* Wq   = (const float*)d_in[1];
  const float* bq   = (const float*)d_in[2];
  const float* Wo   = (const float*)d_in[3];
  const float* bo   = (const float*)d_in[4];
  const float* Wk   = (const float*)d_in[5];
  const float* bk   = (const float*)d_in[6];
  const float* kw1  = (const float*)d_in[7];
  const float* kb1  = (const float*)d_in[8];
  const float* kw2  = (const float*)d_in[9];
  const float* kb2  = (const float*)d_in[10];
  const float* kgAw = (const float*)d_in[11];
  const float* kgAb = (const float*)d_in[12];
  const float* kgBw = (const float*)d_in[13];
  const float* kgBb = (const float*)d_in[14];
  const float* Wv   = (const float*)d_in[15];
  const float* bv   = (const float*)d_in[16];
  const float* vw1  = (const float*)d_in[17];
  const float* vb1  = (const float*)d_in[18];
  const float* vw2  = (const float*)d_in[19];
  const float* vb2  = (const float*)d_in[20];
  const float* vgAw = (const float*)d_in[21];
  const float* vgAb = (const float*)d_in[22];
  const float* vgBw = (const float*)d_in[23];
  const float* vgBb = (const float*)d_in[24];
  float* out = (float*)d_out;

  char* ws = (char*)d_ws;
  const size_t MB = 1024 * 1024;
  ushort* qhb  = (ushort*)(ws);
  ushort* khb  = (ushort*)(ws + 8 * MB);
  ushort* vhb  = (ushort*)(ws + 16 * MB);
  ushort* xb   = (ushort*)(ws + 24 * MB);
  ushort* aob  = (ushort*)(ws + 32 * MB);
  ushort* Wcat = (ushort*)(ws + 40 * MB);  // [5][1024][1024] bf16 = 10 MB
  ushort* Wto  = (ushort*)(ws + 50 * MB);
  ushort* Wtk  = (ushort*)(ws + 52 * MB);
  ushort* Wtv  = (ushort*)(ws + 54 * MB);
  float*  Ak   = (float*)(ws + 56 * MB);
  float*  Bk   = Ak + BB * RNK * DD;
  float*  Av   = Bk + BB * RNK * DD;
  float*  Bv   = Av + BB * RNK * DD;
  float*  zsum = Bv + BB * RNK * DD;            // 2048 floats
  float*  h_pre = zsum + BB * DD;               // 1024 floats
  float*  c_all = h_pre + 4 * 256;              // 256 floats
  float2* tab  = (float2*)(ws + 56 * MB + 512 * 1024);  // 512 KB

  hipMemsetAsync(zsum, 0, (BB * DD + 4 * 256) * sizeof(float), stream);
  z_pool<<<dim3(BB, SS / 16), 256, 0, stream>>>(x, zsum);
  gen_h<<<dim3(4, 8), 256, 0, stream>>>(zsum, kw1, vw1, h_pre);
  hyper_c2<<<4, 256, 0, stream>>>(h_pre, kb1, kw2, kb2, vb1, vw2, vb2, c_all);
  gen_AB<<<dim3(RNK * DD / 256, 4), 256, 0, stream>>>(
      c_all, kgAw, kgAb, kgBw, kgBb, vgAw, vgAb, vgBw, vgBb, Ak, Bk, Av, Bv);

  cvt_bf16<<<(BB * SS * DD / 4) / 256, 256, 0, stream>>>(x, xb);
  cvt_wt<<<dim3(32, 32), 256, 0, stream>>>(Wq, Wcat);
  cvt_wt<<<dim3(32, 32), 256, 0, stream>>>(Wk, Wtk);
  cvt_wt<<<dim3(32, 32), 256, 0, stream>>>(Wv, Wtv);
  cvt_wt<<<dim3(32, 32), 256, 0, stream>>>(Wo, Wto);
  rope_tab<<<(32 * 2048) / 256, 256, 0, stream>>>(tab);
  weff<<<dim3(64, 4), 256, 0, stream>>>(Ak, Bk, Av, Bv, Wtk, Wtv, Wcat);

  // fused q/k/v projection + bias + rope + head-major pack
  gemm_qkv<<<dim3(32, 24), 256, 0, stream>>>(xb, Wcat, bq, bk, bv, tab, qhb,
                                             khb, vhb);
  // attention
  attn_mfma2<<<512, 256, 0, stream>>>(qhb, khb, vhb, aob);
  // output projection
  gemm_out<<<dim3(64, 8), 256, 0, stream>>>(aob, Wto, bo, out);
}

// Round 5
// 325.020 us; speedup vs baseline: 4.7902x; 1.0321x over previous
//
#include <hip/hip_runtime.h>
#include <math.h>

#define BB 2
#define SS 2048
#define DD 1024
#define NH 16
#define HDM 64
#define RNK 8

typedef short short8 __attribute__((ext_vector_type(8)));
typedef float floatx4 __attribute__((ext_vector_type(4)));

static __device__ __forceinline__ ushort f2bf(float f) {
  union { float f; unsigned u; } v;
  v.f = f;
  unsigned r = (v.u + 0x7FFFu + ((v.u >> 16) & 1u)) >> 16;
  return (ushort)r;
}
static __device__ __forceinline__ float bf2f(ushort u) {
  union { unsigned u; float f; } v;
  v.u = ((unsigned)u) << 16;
  return v.f;
}
// pack two floats to bf16x2 by truncation (1 v_perm)
static __device__ __forceinline__ unsigned pack_bf_trunc(float a, float b) {
  union { float f; unsigned u; } x, y;
  x.f = a;
  y.f = b;
  return __builtin_amdgcn_perm(y.u, x.u, 0x07060302u);
}
// pack two floats to bf16x2 with RNE
static __device__ __forceinline__ unsigned pack_bf_rne(float a, float b) {
  union { float f; unsigned u; } x, y;
  x.f = a;
  y.f = b;
  unsigned xu = x.u + 0x7FFFu + ((x.u >> 16) & 1u);
  unsigned yu = y.u + 0x7FFFu + ((y.u >> 16) & 1u);
  return __builtin_amdgcn_perm(yu, xu, 0x07060302u);
}

// ---------------------------------------------------------------------------
// z-pool: zsum[b][d] += sum over 16 rows of x  (256 blocks)
// ---------------------------------------------------------------------------
__global__ __launch_bounds__(256) void z_pool(const float* __restrict__ x,
                                              float* __restrict__ zsum) {
  int b = blockIdx.x;
  int s0 = blockIdx.y * 16;
  int tid = threadIdx.x;
  float p0 = 0.f, p1 = 0.f, p2 = 0.f, p3 = 0.f;
  const float* xp = x + ((size_t)b * SS + s0) * DD;
  for (int s = 0; s < 16; ++s) {
    const float* row = xp + (size_t)s * DD;
    p0 += row[tid];
    p1 += row[tid + 256];
    p2 += row[tid + 512];
    p3 += row[tid + 768];
  }
  atomicAdd(&zsum[b * DD + tid], p0);
  atomicAdd(&zsum[b * DD + tid + 256], p1);
  atomicAdd(&zsum[b * DD + tid + 512], p2);
  atomicAdd(&zsum[b * DD + tid + 768], p3);
}

// ---------------------------------------------------------------------------
// gen_h: h_pre[b][n] += sum over 128-row slice of z[j]*w1[j][n]
// ---------------------------------------------------------------------------
__global__ __launch_bounds__(256) void gen_h(
    const float* __restrict__ zsum,
    const float* __restrict__ kw1, const float* __restrict__ vw1,
    float* __restrict__ h_pre) {
  int b = blockIdx.x & 1;
  int p = (blockIdx.x >> 1) & 1;
  int slice = blockIdx.y;
  const float* w1 = p ? vw1 : kw1;
  int tid = threadIdx.x;
  float acc = 0.f;
  int j0 = slice * 128;
  for (int j = j0; j < j0 + 128; ++j) {
    float z = zsum[b * DD + j] * (1.0f / (float)SS);
    acc += z * w1[j * 256 + tid];
  }
  atomicAdd(&h_pre[(p * 2 + b) * 256 + tid], acc);
}

// ---------------------------------------------------------------------------
// hyper_c2: c = silu(h_pre + b1) @ w2 + b2   (4 blocks)
// ---------------------------------------------------------------------------
__global__ __launch_bounds__(256) void hyper_c2(
    const float* __restrict__ h_pre,
    const float* __restrict__ kb1, const float* __restrict__ kw2,
    const float* __restrict__ kb2,
    const float* __restrict__ vb1, const float* __restrict__ vw2,
    const float* __restrict__ vb2, float* __restrict__ c_all) {
  int p = blockIdx.x >> 1;
  int b = blockIdx.x & 1;
  const float* b1 = p ? vb1 : kb1;
  const float* w2 = p ? vw2 : kw2;
  const float* b2 = p ? vb2 : kb2;
  __shared__ float hs[256];
  __shared__ float part[256];
  int tid = threadIdx.x;
  float hv = h_pre[(p * 2 + b) * 256 + tid] + b1[tid];
  hs[tid] = hv / (1.0f + expf(-hv));
  __syncthreads();
  int n = tid & 63, chunk = tid >> 6;
  float a = 0.f;
  for (int jj = 0; jj < 64; ++jj) {
    int j = chunk * 64 + jj;
    a += hs[j] * w2[j * 64 + n];
  }
  part[tid] = a;
  __syncthreads();
  if (tid < 64) {
    c_all[(p * 2 + b) * 64 + tid] =
        part[tid] + part[tid + 64] + part[tid + 128] + part[tid + 192] + b2[tid];
  }
}

// ---------------------------------------------------------------------------
// gen_AB: A/B = c @ gW + gb  (128 x 4 blocks)
// ---------------------------------------------------------------------------
__global__ __launch_bounds__(256) void gen_AB(
    const float* __restrict__ c_all,
    const float* __restrict__ kgAw, const float* __restrict__ kgAb,
    const float* __restrict__ kgBw, const float* __restrict__ kgBb,
    const float* __restrict__ vgAw, const float* __restrict__ vgAb,
    const float* __restrict__ vgBw, const float* __restrict__ vgBb,
    float* __restrict__ Ak, float* __restrict__ Bk,
    float* __restrict__ Av, float* __restrict__ Bv) {
  int y = blockIdx.y;
  int p = y >> 1, mat = y & 1;
  const float* gw = p ? (mat ? vgBw : vgAw) : (mat ? kgBw : kgAw);
  const float* gb = p ? (mat ? vgBb : vgAb) : (mat ? kgBb : kgAb);
  float* obase = p ? (mat ? Bv : Av) : (mat ? Bk : Ak);

  __shared__ float c0[64], c1[64];
  int tid = threadIdx.x;
  if (tid < 64) c0[tid] = c_all[p * 128 + tid];
  else if (tid < 128) c1[tid - 64] = c_all[p * 128 + tid];
  __syncthreads();

  int idx = blockIdx.x * 256 + tid;
  float a0 = gb[idx], a1 = a0;
#pragma unroll
  for (int j = 0; j < 64; ++j) {
    float w = gw[j * (RNK * DD) + idx];
    a0 += c0[j] * w;
    a1 += c1[j] * w;
  }
  obase[idx] = a0;
  obase[RNK * DD + idx] = a1;
}

// ---------------------------------------------------------------------------
// cvt_bf16: fp32 -> bf16
// ---------------------------------------------------------------------------
__global__ __launch_bounds__(256) void cvt_bf16(const float* __restrict__ in,
                                                ushort* __restrict__ out) {
  int gid = blockIdx.x * 256 + threadIdx.x;
  float4 a = ((const float4*)in)[gid];
  ushort4 o;
  o.x = f2bf(a.x);
  o.y = f2bf(a.y);
  o.z = f2bf(a.z);
  o.w = f2bf(a.w);
  ((ushort4*)out)[gid] = o;
}

// ---------------------------------------------------------------------------
// cvt_wt: W fp32 [K][N] -> Wt bf16 [N][K]
// ---------------------------------------------------------------------------
__global__ __launch_bounds__(256) void cvt_wt(const float* __restrict__ W,
                                              ushort* __restrict__ Wt) {
  __shared__ float tile[32][33];
  int bx = blockIdx.x, by = blockIdx.y;
  int tx = threadIdx.x & 31, ty = threadIdx.x >> 5;
#pragma unroll
  for (int i = 0; i < 4; ++i)
    tile[ty + 8 * i][tx] = W[(size_t)(by * 32 + ty + 8 * i) * DD + bx * 32 + tx];
  __syncthreads();
#pragma unroll
  for (int i = 0; i < 4; ++i)
    Wt[(size_t)(bx * 32 + ty + 8 * i) * DD + by * 32 + tx] =
        f2bf(tile[tx][ty + 8 * i]);
}

// ---------------------------------------------------------------------------
// rope_tab: tab[i][s] = (cos(s*f_i), sin(s*f_i))
// ---------------------------------------------------------------------------
__global__ __launch_bounds__(256) void rope_tab(float2* __restrict__ tab) {
  int gid = blockIdx.x * 256 + threadIdx.x;
  int i = gid >> 11, s = gid & 2047;
  float freq = expf(-(float)i * (9.210340371976184f / 32.0f));
  float sn, cn;
  sincosf((float)s * freq, &sn, &cn);
  tab[gid] = make_float2(cn, sn);
}

// ---------------------------------------------------------------------------
// weff: Wcat[1+2p+b][n][kk] = Wt[n][kk] + (1/8) sum_r Bm[n][r] * A[r][kk]
// ---------------------------------------------------------------------------
__global__ __launch_bounds__(256) void weff(
    const float* __restrict__ Ak, const float* __restrict__ Bk,
    const float* __restrict__ Av, const float* __restrict__ Bv,
    const ushort* __restrict__ Wtk, const ushort* __restrict__ Wtv,
    ushort* __restrict__ Wcat) {
  int y = blockIdx.y;
  int p = y >> 1, b = y & 1;
  const float* A = (p ? Av : Ak) + b * (RNK * DD);
  const float* Bm = (p ? Bv : Bk) + b * (RNK * DD);
  const ushort* src = p ? Wtv : Wtk;
  ushort* dst = Wcat + ((size_t)(1 + 2 * p + b) << 20);

  int tid = threadIdx.x;
  int row = blockIdx.x * 16 + (tid >> 4);
  int cg = tid & 15;
  float bm[RNK];
#pragma unroll
  for (int r = 0; r < RNK; ++r) bm[r] = Bm[row * RNK + r];
  for (int kk = cg * 64; kk < cg * 64 + 64; kk += 4) {
    float4 acc = make_float4(0.f, 0.f, 0.f, 0.f);
#pragma unroll
    for (int r = 0; r < RNK; ++r) {
      float4 a4 = *(const float4*)&A[r * DD + kk];
      acc.x += bm[r] * a4.x;
      acc.y += bm[r] * a4.y;
      acc.z += bm[r] * a4.z;
      acc.w += bm[r] * a4.w;
    }
    ushort4 ws = *(const ushort4*)&src[(size_t)row * DD + kk];
    ushort4 o;
    o.x = f2bf(bf2f(ws.x) + acc.x * 0.125f);
    o.y = f2bf(bf2f(ws.y) + acc.y * 0.125f);
    o.z = f2bf(bf2f(ws.z) + acc.z * 0.125f);
    o.w = f2bf(bf2f(ws.w) + acc.w * 0.125f);
    *(ushort4*)&dst[(size_t)row * DD + kk] = o;
  }
}

// ---------------------------------------------------------------------------
// gemm_qkv: fused q/k/v projection. grid (32, 24). ny: 0-7 q, 8-15 k, 16-23 v.
// ---------------------------------------------------------------------------
__global__ __launch_bounds__(256) void gemm_qkv(
    const ushort* __restrict__ Axb, const ushort* __restrict__ Wcat,
    const float* __restrict__ bq, const float* __restrict__ bk,
    const float* __restrict__ bv, const float2* __restrict__ tab,
    ushort* __restrict__ qhb, ushort* __restrict__ khb,
    ushort* __restrict__ vhb) {
  __shared__ ushort As[128][40];
  __shared__ ushort Bs[128][40];
  int tid = threadIdx.x;
  int bm = blockIdx.x * 128;
  int ny = blockIdx.y;
  int path = ny >> 3;
  int nb = (ny & 7) * 128;
  int b_blk = bm >> 11;
  const ushort* Wbase =
      (path == 0) ? Wcat : Wcat + ((size_t)(1 + (path - 1) * 2 + b_blk) << 20);
  const float* bias = (path == 0) ? bq : (path == 1 ? bk : bv);
  ushort* outp = (path == 0) ? qhb : (path == 1 ? khb : vhb);

  int w = tid >> 6, lane = tid & 63, l16 = lane & 15, q4 = lane >> 4;
  int wm = (w >> 1) * 64, wn = (w & 1) * 64;
  floatx4 acc[4][4];
#pragma unroll
  for (int mi = 0; mi < 4; ++mi)
#pragma unroll
    for (int ni = 0; ni < 4; ++ni) acc[mi][ni] = 0;

  int sr = tid >> 2, sc = (tid & 3) * 8;
  const ushort* Ap0 = Axb + (size_t)(bm + sr) * DD + sc;
  const ushort* Ap1 = Axb + (size_t)(bm + sr + 64) * DD + sc;
  const ushort* Bp0 = Wbase + (size_t)(nb + sr) * DD + sc;
  const ushort* Bp1 = Wbase + (size_t)(nb + sr + 64) * DD + sc;

  for (int k0 = 0; k0 < DD; k0 += 32) {
    uint4 a0 = *(const uint4*)(Ap0 + k0);
    uint4 a1 = *(const uint4*)(Ap1 + k0);
    uint4 b0 = *(const uint4*)(Bp0 + k0);
    uint4 b1 = *(const uint4*)(Bp1 + k0);
    __syncthreads();
    *(uint4*)&As[sr][sc] = a0;
    *(uint4*)&As[sr + 64][sc] = a1;
    *(uint4*)&Bs[sr][sc] = b0;
    *(uint4*)&Bs[sr + 64][sc] = b1;
    __syncthreads();
    short8 af[4], bf[4];
#pragma unroll
    for (int mi = 0; mi < 4; ++mi)
      af[mi] = *(const short8*)&As[wm + mi * 16 + l16][q4 * 8];
#pragma unroll
    for (int ni = 0; ni < 4; ++ni)
      bf[ni] = *(const short8*)&Bs[wn + ni * 16 + l16][q4 * 8];
#pragma unroll
    for (int mi = 0; mi < 4; ++mi)
#pragma unroll
      for (int ni = 0; ni < 4; ++ni)
        acc[mi][ni] = __builtin_amdgcn_mfma_f32_16x16x32_bf16(
            af[mi], bf[ni], acc[mi][ni], 0, 0, 0);
  }

  int h = (nb + wn) >> 6;
  float biasv[4];
#pragma unroll
  for (int ni = 0; ni < 4; ++ni) biasv[ni] = bias[nb + wn + ni * 16 + l16];

#pragma unroll
  for (int mi = 0; mi < 4; ++mi) {
#pragma unroll
    for (int r = 0; r < 4; ++r) {
      int grow = bm + wm + mi * 16 + q4 * 4 + r;
      int bb = grow >> 11, s = grow & 2047;
      ushort* orow = outp + (((size_t)(bb * NH + h) * SS + s) << 6);
      float v[4];
#pragma unroll
      for (int ni = 0; ni < 4; ++ni) v[ni] = acc[mi][ni][r] + biasv[ni];
      if (path < 2) {
#pragma unroll
        for (int ni = 0; ni < 2; ++ni) {
          float2 cs = tab[((ni * 16 + l16) << 11) + s];
          float a = v[ni] * cs.x - v[ni + 2] * cs.y;
          float c = v[ni + 2] * cs.x + v[ni] * cs.y;
          v[ni] = a;
          v[ni + 2] = c;
        }
      }
#pragma unroll
      for (int ni = 0; ni < 4; ++ni) orow[ni * 16 + l16] = f2bf(v[ni]);
    }
  }
}

// ---------------------------------------------------------------------------
// attn_mfma3: causal flash attention via S^T = K*Q^T and O^T = V^T*P^T.
// Block = 64 queries (2 waves x 32q), 64-key tiles, no-max softmax.
// - P stays per-wave (no barrier): C-frag of S^T has 4 consecutive keys/lane
//   -> ds_write_b64; P^T B-frags are contiguous ds_read_b128.
// - K fragments loaded directly from global (no LDS), prefetched 1 tile ahead.
// - V transposed into double-buffered LDS -> 1 barrier per tile.
// grid 1024 = 32 q0-stripes (heavy first) x 32 (b,h)
// ---------------------------------------------------------------------------
#define VT_IDX(d, c) ((unsigned)(72 * (d) + 16 * ((d) >> 3) + (c)))

__global__ __launch_bounds__(128) void attn_mfma3(
    const ushort* __restrict__ qh, const ushort* __restrict__ kh,
    const ushort* __restrict__ vh, ushort* __restrict__ ao) {
  __shared__ ushort Ps[64][72];
  __shared__ ushort Vt[2][4720];
  int bid = blockIdx.x;
  int bh = bid & 31;
  int q0 = (31 - (bid >> 5)) * 64;  // heavy-first
  int b = bh >> 4, h = bh & 15;
  int tid = threadIdx.x;
  int w = tid >> 6, lane = tid & 63, l16 = lane & 15, q4 = lane >> 4;
  int nkt = (q0 >> 6) + 1;

  const ushort* kbase = kh + (size_t)bh * SS * HDM;
  const ushort* vbase = vh + (size_t)bh * SS * HDM;

  // Q as B-operand fragments: lane n=query(l16), k-regs = d = 32*hf + 8*q4+j
  short8 qf[2][2];
#pragma unroll
  for (int qi = 0; qi < 2; ++qi) {
    const ushort* qrow = qh + ((size_t)bh * SS + q0 + 32 * w + 16 * qi + l16) * HDM;
    qf[qi][0] = *(const short8*)(qrow + 8 * q4);
    qf[qi][1] = *(const short8*)(qrow + 32 + 8 * q4);
  }

  // V staging indices: so8 = d-chunk, sp*4.. rows
  int so8 = tid & 7, sp = (tid >> 3) & 15;

  // prime tile 0: K frags + V regs
  short8 kf[4][2];
#pragma unroll
  for (int ki = 0; ki < 4; ++ki) {
    const ushort* kr = kbase + (size_t)(16 * ki + l16) * HDM + 8 * q4;
    kf[ki][0] = *(const short8*)(kr);
    kf[ki][1] = *(const short8*)(kr + 32);
  }
  uint4 vr[4];
#pragma unroll
  for (int j = 0; j < 4; ++j)
    vr[j] = *(const uint4*)(vbase + (size_t)(4 * sp + j) * HDM + 8 * so8);
  // write V(0) into buf 0 (transposed, pair-packed)
#pragma unroll
  for (int j = 0; j < 4; j += 2) {
    const ushort* pa = (const ushort*)&vr[j];
    const ushort* pb = (const ushort*)&vr[j + 1];
#pragma unroll
    for (int dd = 0; dd < 8; ++dd) {
      int d = so8 * 8 + dd;
      *(unsigned*)&Vt[0][VT_IDX(d, 4 * sp + j)] =
          (unsigned)pa[dd] | ((unsigned)pb[dd] << 16);
    }
  }
  __syncthreads();

  floatx4 o[4][2];  // [di][qi], C-layout: row=d(4*q4+r), col=query(l16)
#pragma unroll
  for (int di = 0; di < 4; ++di)
#pragma unroll
    for (int qi = 0; qi < 2; ++qi) o[di][qi] = 0;
  float l_part[2] = {0.f, 0.f};

  for (int kt = 0; kt < nkt; ++kt) {
    int buf = kt & 1;
    bool has_next = (kt + 1) < nkt;
    short8 kn[4][2];
    if (has_next) {
      int k0n = (kt + 1) * 64;
#pragma unroll
      for (int ki = 0; ki < 4; ++ki) {
        const ushort* kr = kbase + (size_t)(k0n + 16 * ki + l16) * HDM + 8 * q4;
        kn[ki][0] = *(const short8*)(kr);
        kn[ki][1] = *(const short8*)(kr + 32);
      }
#pragma unroll
      for (int j = 0; j < 4; ++j)
        vr[j] = *(const uint4*)(vbase + (size_t)(k0n + 4 * sp + j) * HDM + 8 * so8);
    }

    // S^T = K * Q^T : D[key][query]
    floatx4 s4[2][4];
#pragma unroll
    for (int ki = 0; ki < 4; ++ki)
#pragma unroll
      for (int qi = 0; qi < 2; ++qi) {
        floatx4 c;
        c = 0;
        c = __builtin_amdgcn_mfma_f32_16x16x32_bf16(kf[ki][0], qf[qi][0], c, 0, 0, 0);
        c = __builtin_amdgcn_mfma_f32_16x16x32_bf16(kf[ki][1], qf[qi][1], c, 0, 0, 0);
        s4[qi][ki] = c;
      }

    // softmax (no-max): p = 2^(s*0.125*log2e); per-lane l partials
    bool diag = (kt == nkt - 1);
#pragma unroll
    for (int qi = 0; qi < 2; ++qi) {
      int qloc = 32 * w + 16 * qi + l16;  // query within block
      float lp = 0.f;
#pragma unroll
      for (int ki = 0; ki < 4; ++ki) {
        float p[4];
#pragma unroll
        for (int r = 0; r < 4; ++r) {
          float t = s4[qi][ki][r] * 0.18033688f;
          float pv = exp2f(t);
          if (diag && (16 * ki + 4 * q4 + r) > qloc) pv = 0.f;
          p[r] = pv;
          lp += pv;
        }
        unsigned u0 = pack_bf_trunc(p[0], p[1]);
        unsigned u1 = pack_bf_trunc(p[2], p[3]);
        uint2 u2;
        u2.x = u0;
        u2.y = u1;
        *(uint2*)&Ps[qloc][16 * ki + 4 * q4] = u2;
      }
      l_part[qi] += lp;
    }

    // O^T += V^T * P^T
#pragma unroll
    for (int qi = 0; qi < 2; ++qi) {
      short8 pf0 = *(const short8*)&Ps[32 * w + 16 * qi + l16][8 * q4];
      short8 pf1 = *(const short8*)&Ps[32 * w + 16 * qi + l16][32 + 8 * q4];
#pragma unroll
      for (int di = 0; di < 4; ++di) {
        short8 vf0 = *(const short8*)&Vt[buf][VT_IDX(16 * di + l16, 8 * q4)];
        short8 vf1 = *(const short8*)&Vt[buf][VT_IDX(16 * di + l16, 32 + 8 * q4)];
        o[di][qi] =
            __builtin_amdgcn_mfma_f32_16x16x32_bf16(vf0, pf0, o[di][qi], 0, 0, 0);
        o[di][qi] =
            __builtin_amdgcn_mfma_f32_16x16x32_bf16(vf1, pf1, o[di][qi], 0, 0, 0);
      }
    }

    if (has_next) {
      int nb = (kt + 1) & 1;
#pragma unroll
      for (int j = 0; j < 4; j += 2) {
        const ushort* pa = (const ushort*)&vr[j];
        const ushort* pb = (const ushort*)&vr[j + 1];
#pragma unroll
        for (int dd = 0; dd < 8; ++dd) {
          int d = so8 * 8 + dd;
          *(unsigned*)&Vt[nb][VT_IDX(d, 4 * sp + j)] =
              (unsigned)pa[dd] | ((unsigned)pb[dd] << 16);
        }
      }
#pragma unroll
      for (int ki = 0; ki < 4; ++ki) {
        kf[ki][0] = kn[ki][0];
        kf[ki][1] = kn[ki][1];
      }
    }
    __syncthreads();
  }

  // l reduce across q4 groups (lanes sharing l16), normalize, store O
#pragma unroll
  for (int qi = 0; qi < 2; ++qi) {
    float l = l_part[qi];
    l += __shfl_xor(l, 16);
    l += __shfl_xor(l, 32);
    float inv = 1.0f / l;
    int token = q0 + 32 * w + 16 * qi + l16;
    ushort* orow = ao + ((size_t)(b * SS + token)) * DD + h * HDM;
#pragma unroll
    for (int di = 0; di < 4; ++di) {
      floatx4 ov = o[di][qi];
      uint2 u2;
      u2.x = pack_bf_rne(ov[0] * inv, ov[1] * inv);
      u2.y = pack_bf_rne(ov[2] * inv, ov[3] * inv);
      *(uint2*)&orow[16 * di + 4 * q4] = u2;
    }
  }
}

// ---------------------------------------------------------------------------
// gemm_out: C[M][N] fp32 = A bf16 @ Wt^T + bias. 64x128 tile, grid (64, 8).
// ---------------------------------------------------------------------------
__global__ __launch_bounds__(256) void gemm_out(
    const ushort* __restrict__ A, const ushort* __restrict__ Bt,
    const float* __restrict__ bias, float* __restrict__ C) {
  __shared__ ushort As[64][40];
  __shared__ ushort Bs[128][40];
  int tid = threadIdx.x;
  int bm = blockIdx.x * 64, bn = blockIdx.y * 128;
  int w = tid >> 6, lane = tid & 63, l16 = lane & 15, q4 = lane >> 4;
  int wm = (w >> 1) * 32, wn = (w & 1) * 64;
  floatx4 acc[2][4];
#pragma unroll
  for (int mi = 0; mi < 2; ++mi)
#pragma unroll
    for (int ni = 0; ni < 4; ++ni) acc[mi][ni] = 0;

  int sr = tid >> 2, sc = (tid & 3) * 8;
  const ushort* Ap0 = A + (size_t)(bm + sr) * DD + sc;
  const ushort* Bp0 = Bt + (size_t)(bn + sr) * DD + sc;
  const ushort* Bp1 = Bt + (size_t)(bn + sr + 64) * DD + sc;

  for (int k0 = 0; k0 < DD; k0 += 32) {
    uint4 a0 = *(const uint4*)(Ap0 + k0);
    uint4 b0 = *(const uint4*)(Bp0 + k0);
    uint4 b1 = *(const uint4*)(Bp1 + k0);
    __syncthreads();
    *(uint4*)&As[sr & 63][sc] = a0;
    *(uint4*)&Bs[sr][sc] = b0;
    *(uint4*)&Bs[sr + 64][sc] = b1;
    __syncthreads();
    short8 af[2], bf[4];
#pragma unroll
    for (int mi = 0; mi < 2; ++mi)
      af[mi] = *(const short8*)&As[wm + mi * 16 + l16][q4 * 8];
#pragma unroll
    for (int ni = 0; ni < 4; ++ni)
      bf[ni] = *(const short8*)&Bs[wn + ni * 16 + l16][q4 * 8];
#pragma unroll
    for (int mi = 0; mi < 2; ++mi)
#pragma unroll
      for (int ni = 0; ni < 4; ++ni)
        acc[mi][ni] = __builtin_amdgcn_mfma_f32_16x16x32_bf16(
            af[mi], bf[ni], acc[mi][ni], 0, 0, 0);
  }
#pragma unroll
  for (int mi = 0; mi < 2; ++mi) {
#pragma unroll
    for (int r = 0; r < 4; ++r) {
      int row = bm + wm + mi * 16 + q4 * 4 + r;
      float* Cr = C + (size_t)row * DD;
#pragma unroll
      for (int ni = 0; ni < 4; ++ni) {
        int col = bn + wn + ni * 16 + l16;
        Cr[col] = acc[mi][ni][r] + bias[col];
      }
    }
  }
}

// ---------------------------------------------------------------------------
extern "C" void kernel_launch(void* const* d_in, const int* in_sizes, int n_in,
                              void* d_out, int out_size, void* d_ws,
                              size_t ws_size, hipStream_t stream) {
  const float* x    = (const float*)d_in[0];
  const float* Wq   = (const float*)d_in[1];
  const float* bq   = (const float*)d_in[2];
  const float* Wo   = (const float*)d_in[3];
  const float* bo   = (const float*)d_in[4];
  const float* Wk   = (const float*)d_in[5];
  const float* bk   = (const float*)d_in[6];
  const float* kw1  = (const float*)d_in[7];
  const float* kb1  = (const float*)d_in[8];
  const float* kw2  = (const float*)d_in[9];
  const float* kb2  = (const float*)d_in[10];
  const float* kgAw = (const float*)d_in[11];
  const float* kgAb = (const float*)d_in[12];
  const float* kgBw = (const float*)d_in[13];
  const float* kgBb = (const float*)d_in[14];
  const float* Wv   = (const float*)d_in[15];
  const float* bv   = (const float*)d_in[16];
  const float* vw1  = (const float*)d_in[17];
  const float* vb1  = (const float*)d_in[18];
  const float* vw2  = (const float*)d_in[19];
  const float* vb2  = (const float*)d_in[20];
  const float* vgAw = (const float*)d_in[21];
  const float* vgAb = (const float*)d_in[22];
  const float* vgBw = (const float*)d_in[23];
  const float* vgBb = (const float*)d_in[24];
  float* out = (float*)d_out;

  char* ws = (char*)d_ws;
  const size_t MB = 1024 * 1024;
  ushort* qhb  = (ushort*)(ws);
  ushort* khb  = (ushort*)(ws + 8 * MB);
  ushort* vhb  = (ushort*)(ws + 16 * MB);
  ushort* xb   = (ushort*)(ws + 24 * MB);
  ushort* aob  = (ushort*)(ws + 32 * MB);
  ushort* Wcat = (ushort*)(ws + 40 * MB);  // [5][1024][1024] bf16 = 10 MB
  ushort* Wto  = (ushort*)(ws + 50 * MB);
  ushort* Wtk  = (ushort*)(ws + 52 * MB);
  ushort* Wtv  = (ushort*)(ws + 54 * MB);
  float*  Ak   = (float*)(ws + 56 * MB);
  float*  Bk   = Ak + BB * RNK * DD;
  float*  Av   = Bk + BB * RNK * DD;
  float*  Bv   = Av + BB * RNK * DD;
  float*  zsum = Bv + BB * RNK * DD;
  float*  h_pre = zsum + BB * DD;
  float*  c_all = h_pre + 4 * 256;
  float2* tab  = (float2*)(ws + 56 * MB + 512 * 1024);

  hipMemsetAsync(zsum, 0, (BB * DD + 4 * 256) * sizeof(float), stream);
  z_pool<<<dim3(BB, SS / 16), 256, 0, stream>>>(x, zsum);
  gen_h<<<dim3(4, 8), 256, 0, stream>>>(zsum, kw1, vw1, h_pre);
  hyper_c2<<<4, 256, 0, stream>>>(h_pre, kb1, kw2, kb2, vb1, vw2, vb2, c_all);
  gen_AB<<<dim3(RNK * DD / 256, 4), 256, 0, stream>>>(
      c_all, kgAw, kgAb, kgBw, kgBb, vgAw, vgAb, vgBw, vgBb, Ak, Bk, Av, Bv);

  cvt_bf16<<<(BB * SS * DD / 4) / 256, 256, 0, stream>>>(x, xb);
  cvt_wt<<<dim3(32, 32), 256, 0, stream>>>(Wq, Wcat);
  cvt_wt<<<dim3(32, 32), 256, 0, stream>>>(Wk, Wtk);
  cvt_wt<<<dim3(32, 32), 256, 0, stream>>>(Wv, Wtv);
  cvt_wt<<<dim3(32, 32), 256, 0, stream>>>(Wo, Wto);
  rope_tab<<<(32 * 2048) / 256, 256, 0, stream>>>(tab);
  weff<<<dim3(64, 4), 256, 0, stream>>>(Ak, Bk, Av, Bv, Wtk, Wtv, Wcat);

  gemm_qkv<<<dim3(32, 24), 256, 0, stream>>>(xb, Wcat, bq, bk, bv, tab, qhb,
                                             khb, vhb);
  attn_mfma3<<<1024, 128, 0, stream>>>(qhb, khb, vhb, aob);
  gemm_out<<<dim3(64, 8), 256, 0, stream>>>(aob, Wto, bo, out);
}